// Round 2
// baseline (1668.260 us; speedup 1.0000x reference)
//
#include <hip/hip_runtime.h>
#include <math.h>

#pragma clang fp contract(off)

#define BB 32
#define CC 64
#define LL 8192
#define NW 1021      // number of spectral windows: (8192-32)/8 + 1
#define MAXSEG 1024
#define MAXTOK 1024
#define BNDCAP 1026
#define NBINS (LL / 2)   // 4096 flat bins per batch (segments partition [0,L))

// DP blocking parameters
#define DP_T 64          // ends per block
#define DP_NBLK 16       // ceil(NW / DP_T)
#define DP_NWAVE 8       // waves per workgroup (512 threads)
#define NWORDS 16        // 16 x 64-bit mask words cover j in [0,1024)
#define DP_SAFE 1e-6     // PELT prune margin; eval rounding is <= ~1e-11

// ---------------------------------------------------------------------------
// numpy pairwise_sum replica (loops.c.src): n<8 sequential, n<=128 blocked with
// 8 accumulators, else recursive halving with n2 -= n2 % 8.
// ---------------------------------------------------------------------------
template <typename F>
__device__ double np_pairwise(const F& f, int off, int n) {
  if (n < 8) {
    double res = 0.0;
    for (int i = 0; i < n; i++) res = res + f(off + i);
    return res;
  }
  if (n <= 128) {
    double r0 = f(off + 0), r1 = f(off + 1), r2 = f(off + 2), r3 = f(off + 3);
    double r4 = f(off + 4), r5 = f(off + 5), r6 = f(off + 6), r7 = f(off + 7);
    int i = 8;
    int lim = n - (n % 8);
    for (; i < lim; i += 8) {
      r0 = r0 + f(off + i + 0); r1 = r1 + f(off + i + 1);
      r2 = r2 + f(off + i + 2); r3 = r3 + f(off + i + 3);
      r4 = r4 + f(off + i + 4); r5 = r5 + f(off + i + 5);
      r6 = r6 + f(off + i + 6); r7 = r7 + f(off + i + 7);
    }
    double res = ((r0 + r1) + (r2 + r3)) + ((r4 + r5) + (r6 + r7));
    for (; i < n; i++) res = res + f(off + i);
    return res;
  }
  int n2 = n / 2;
  n2 -= n2 % 8;
  return np_pairwise(f, off, n2) + np_pairwise(f, off + n2, n - n2);
}

// Exact per-candidate SSE, op-order identical to numpy reference:
// per channel t_c = (q_e - q_j) - (p_e - p_j)^2 / sl, then (t0+t1)+t2.
__device__ __forceinline__ double dp_sse(const double* __restrict__ preL,
                                         const double* __restrict__ pre2L,
                                         double pe0, double pe1, double pe2,
                                         double qe0, double qe1, double qe2,
                                         int j, double sl) {
  double s0 = pe0 - preL[j * 3 + 0];
  double s1 = pe1 - preL[j * 3 + 1];
  double s2 = pe2 - preL[j * 3 + 2];
  double u0 = s0 * s0, u1 = s1 * s1, u2 = s2 * s2;
  double t0 = (qe0 - pre2L[j * 3 + 0]) - u0 / sl;
  double t1 = (qe1 - pre2L[j * 3 + 1]) - u1 / sl;
  double t2 = (qe2 - pre2L[j * 3 + 2]) - u2 / sl;
  return (t0 + t1) + t2;
}

// ---------------------------------------------------------------------------
// Stage 1: agg[b][l] = channel mean, numpy sequential f32 order.
// ---------------------------------------------------------------------------
__global__ void k_agg(const float* __restrict__ x, double* __restrict__ agg) {
  int idx = blockIdx.x * blockDim.x + threadIdx.x;
  if (idx >= BB * LL) return;
  int b = idx / LL, l = idx - b * LL;
  const float* xb = x + (size_t)b * CC * LL + l;
  float s = 0.0f;
  for (int c = 0; c < CC; c++) s = s + xb[(size_t)c * LL];
  agg[idx] = (double)(s / 64.0f);
}

// ---------------------------------------------------------------------------
// Stage 2: per-window spectral features (32-pt DFT, bins 1..16).
// ---------------------------------------------------------------------------
__global__ void k_winfeat(const double* __restrict__ agg, double* __restrict__ feat) {
  __shared__ double tc[32], tsn[32];
  if (threadIdx.x < 32) {
    double th = 6.283185307179586 * ((double)threadIdx.x / 32.0);
    tc[threadIdx.x] = cos(th);
    tsn[threadIdx.x] = sin(th);
  }
  __syncthreads();
  int idx = blockIdx.x * blockDim.x + threadIdx.x;
  if (idx >= BB * NW) return;
  int b = idx / NW, w = idx - b * NW;
  const double* a = agg + (size_t)b * LL + (size_t)w * 8;
  double av[32];
#pragma unroll
  for (int t = 0; t < 32; t++) av[t] = a[t];
  double p[16];
  for (int k = 1; k <= 16; k++) {
    double re = 0.0, im = 0.0;
    int m = 0;
    for (int t = 0; t < 32; t++) {
      re = re + av[t] * tc[m];
      im = im + av[t] * tsn[m];
      m = (m + k) & 31;
    }
    p[k - 1] = re * re + im * im;
  }
  double r[8];
  for (int i = 0; i < 8; i++) r[i] = p[i] + p[i + 8];
  double sum = ((r[0] + r[1]) + (r[2] + r[3])) + ((r[4] + r[5]) + (r[6] + r[7]));
  double tot = (sum > 1e-8) ? sum : 1e-8;
  double pf[16];
  for (int i = 0; i < 16; i++) pf[i] = p[i] * (double)(i + 1);
  for (int i = 0; i < 8; i++) r[i] = pf[i] + pf[i + 8];
  double spf = ((r[0] + r[1]) + (r[2] + r[3])) + ((r[4] + r[5]) + (r[6] + r[7]));
  int dom = 0;
  double bv = p[0];
  for (int i = 1; i < 16; i++)
    if (p[i] > bv) { bv = p[i]; dom = i; }
  dom += 1;
  double cent = spf / tot;
  double q[16];
  for (int i = 0; i < 16; i++) {
    double d = (double)(i + 1) - cent;
    double dd = d * d;
    q[i] = dd * p[i];
  }
  for (int i = 0; i < 8; i++) r[i] = q[i] + q[i + 8];
  double sv = ((r[0] + r[1]) + (r[2] + r[3])) + ((r[4] + r[5]) + (r[6] + r[7]));
  double var = sv / tot;
  double bw = sqrt(var > 0.0 ? var : 0.0) / 32.0;
  double mean = sum / 16.0;
  double* f = feat + ((size_t)b * NW + (size_t)w) * 3;
  f[0] = (double)dom / 32.0;
  f[1] = bw;
  f[2] = log1p(mean);
}

// ---------------------------------------------------------------------------
// Stage 3: PELT DP, blocked + exact pruning.
//  * Pruning: j is dropped once dp[j] + C(j,t) > dp[t] + DP_SAFE at a block
//    boundary t. C from prefix arrays satisfies C(s,u) >= C(s,t) + C(t,u)
//    EXACTLY in real arithmetic for arbitrary prefix values (Q telescopes;
//    P-gap = (Aq-Bp)^2/(pq(p+q)) >= 0), so with SAFE=1e-6 >> eval rounding
//    (~1e-11) a pruned j can never be the fp argmin at any future end: dp
//    values, argmins and first-occurrence ties are bit-identical.
//  * Survivors tracked as a 16-word LDS bitmask; Phase A iterates set bits
//    only (wave-uniform ctz loop - skipped candidates are ~free).
//  * Phase B: the 64x64 triangle's sse values are precomputed in parallel by
//    all 8 waves into sseT before the barrier; the serial chain is just
//    shfl + add + min with the sseT load double-buffered one step ahead.
//  * pvL/pixL padded to stride 9 (2-way LDS aliasing = free) - r1's 278k
//    bank conflicts came from the unpadded stride-8 merge arrays.
// ---------------------------------------------------------------------------
__global__ __launch_bounds__(512) void k_dp(const double* __restrict__ feat,
                                            int* __restrict__ bnd_g,
                                            int* __restrict__ nbnd_g,
                                            int* __restrict__ seg_s,
                                            int* __restrict__ seg_e,
                                            int* __restrict__ nseg_g) {
  __shared__ double preL[(NW + 1) * 3];
  __shared__ double pre2L[(NW + 1) * 3];
  __shared__ double dpL[NW + 1];
  __shared__ int prevL[NW + 1];
  __shared__ double sseT[DP_T][DP_T + 1];   // 33 KB; also feat staging buffer
  __shared__ double pvL[DP_T][DP_NWAVE + 1];
  __shared__ int pixL[DP_T][DP_NWAVE + 1];
  __shared__ unsigned long long maskL[NWORDS];
  int b = blockIdx.x;
  int tid = threadIdx.x;
  const double* fb = feat + (size_t)b * NW * 3;

  // Stage feat into LDS (coalesced), init mask + dp[0].
  double* featS = &sseT[0][0];  // 4160 doubles >= NW*3 = 3063
  for (int i = tid; i < NW * 3; i += 512) featS[i] = fb[i];
  if (tid < NWORDS) maskL[tid] = ~0ull;
  if (tid == 0) dpL[0] = -1.0;
  __syncthreads();

  // Parallel prefix: 6 independent sequential chains (3 ch x {sum, sumsq}),
  // per-channel order identical to np.cumsum -> bit-exact. Reads LDS-staged
  // feat so the dependent fp64 add chain is the only latency.
  if (tid < 6) {
    int c = tid % 3;
    bool sq = tid >= 3;
    double* dst = sq ? pre2L : preL;
    dst[c] = 0.0;
    double acc = 0.0;
    for (int i = 0; i < NW; i++) {
      double f = featS[i * 3 + c];
      double v = sq ? f * f : f;
      acc = acc + v;
      dst[(i + 1) * 3 + c] = acc;
    }
  }
  __syncthreads();

  int lane = tid & 63;   // end offset within block
  int w = tid >> 6;      // wave id
  double dpLast = -1.0;  // dp[e0] seen by wave 0 at phase-B entry (dp[0] = -1)

  for (int blk = 0; blk < DP_NBLK; blk++) {
    int e0 = blk * DP_T;
    int ecnt = NW - e0;
    if (ecnt > DP_T) ecnt = DP_T;
    int end = e0 + 1 + lane;
    if (end > NW) end = NW;  // clamp for safe addressing; writes are guarded
    double pe0 = preL[end * 3 + 0], pe1 = preL[end * 3 + 1], pe2 = preL[end * 3 + 2];
    double qe0 = pre2L[end * 3 + 0], qe1 = pre2L[end * 3 + 1], qe2 = pre2L[end * 3 + 2];
    double v = __builtin_inf();
    int ix = 0;
    // Phase A: surviving candidates j < e0. Wave w owns mask words w, w+8.
    for (int wi = 0; wi < 2; wi++) {
      int word = w + wi * 8;
      int jbase = word << 6;
      if (jbase >= e0) continue;  // e0 is a multiple of 64: full words only
      unsigned long long m = maskL[word];
      while (m) {
        int bit = __builtin_ctzll(m);
        m &= m - 1;
        int j = jbase + bit;
        double sl = (double)(end - j);
        double sse = dp_sse(preL, pre2L, pe0, pe1, pe2, qe0, qe1, qe2, j, sl);
        double cand = (dpL[j] + sse) + 1.0;
        if (cand < v || (cand == v && j < ix)) { v = cand; ix = j; }
      }
    }
    pvL[lane][w] = v;
    pixL[lane][w] = ix;
    // Triangle precompute (parallel): sse(j=e0+s, end) for this block.
    // Entries with s > lane produce inf/nan (sl <= 0) and are masked later.
    for (int s = w; s < ecnt; s += DP_NWAVE) {
      int j = e0 + s;
      double sl = (double)(end - j);
      sseT[s][lane] = dp_sse(preL, pre2L, pe0, pe1, pe2, qe0, qe1, qe2, j, sl);
    }
    __syncthreads();
    if (w == 0) {
      // Merge wave partials: global first-occurrence argmin via ix tie-break.
      double vcur = pvL[lane][0];
      int ixcur = pixL[lane][0];
#pragma unroll
      for (int t = 1; t < DP_NWAVE; t++) {
        double ov = pvL[lane][t];
        int oi = pixL[lane][t];
        if (ov < vcur || (ov == vcur && oi < ixcur)) { vcur = ov; ixcur = oi; }
      }
      // Phase B: serial chain over the triangle; critical path is only
      // shfl + add + cmp (sse precomputed, load double-buffered 1 ahead).
      double sse_next = sseT[0][lane];
      for (int s = 0; s < ecnt; s++) {
        double sse_cur = sse_next;
        if (s + 1 < ecnt) sse_next = sseT[s + 1][lane];
        double dpj = (s == 0) ? dpLast : __shfl(vcur, s - 1, 64);
        double cand = (dpj + sse_cur) + 1.0;
        if (lane >= s && cand < vcur) { vcur = cand; ixcur = e0 + s; }
        if (lane == s) {
          dpL[end] = vcur;
          prevL[end] = ixcur;
        }
      }
      dpLast = __shfl(vcur, ecnt - 1, 64);  // dp[e0 + ecnt] for next block
    }
    __syncthreads();
    // Prune at t_ref = e0 + ecnt (skip after last block).
    if (blk < DP_NBLK - 1) {
      int tref = e0 + ecnt;
      double pt0 = preL[tref * 3 + 0], pt1 = preL[tref * 3 + 1], pt2 = preL[tref * 3 + 2];
      double qt0 = pre2L[tref * 3 + 0], qt1 = pre2L[tref * 3 + 1], qt2 = pre2L[tref * 3 + 2];
      double dpt = dpL[tref];
      unsigned long long old0 = maskL[w];
      unsigned long long old8 = maskL[w + 8];
      bool k0 = true;
      {
        int j = tid;
        if (j < tref) {
          bool ob = (old0 >> lane) & 1ull;
          double sl = (double)(tref - j);
          double sse = dp_sse(preL, pre2L, pt0, pt1, pt2, qt0, qt1, qt2, j, sl);
          k0 = ob && ((dpL[j] + sse) <= dpt + DP_SAFE);
        }
      }
      unsigned long long nm0 = __ballot(k0);
      if (lane == 0) maskL[w] = nm0;
      bool k1 = true;
      {
        int j = tid + 512;
        if (j < tref) {
          bool ob = (old8 >> lane) & 1ull;
          double sl = (double)(tref - j);
          double sse = dp_sse(preL, pre2L, pt0, pt1, pt2, qt0, qt1, qt2, j, sl);
          k1 = ob && ((dpL[j] + sse) <= dpt + DP_SAFE);
        }
      }
      unsigned long long nm1 = __ballot(k1);
      if (lane == 0) maskL[w + 8] = nm1;
    }
    __syncthreads();
  }

  if (tid == 0) {
    int* chain = (int*)preL;  // reuse LDS
    int cnt = 0, i = NW;
    while (i > 0) { i = prevL[i]; chain[cnt++] = i; }
    int* bbL = (int*)pre2L;   // reuse LDS
    int nb = 0;
    bbL[nb++] = 0;
    for (int t = cnt - 2; t >= 0; t--) {  // interior breakpoints, ascending
      int w2 = chain[t];
      int tt = w2 * 8;
      if (tt <= bbL[nb - 1]) continue;
      if (tt - bbL[nb - 1] < 8) continue;
      if (LL - tt < 8) continue;
      bbL[nb++] = tt;
    }
    bbL[nb++] = LL;
    int* bb = bnd_g + (size_t)b * BNDCAP;
    for (int t = 0; t < nb; t++) bb[t] = bbL[t];
    nbnd_g[b] = nb;
    int nseg = nb - 1;
    nseg_g[b] = nseg;
    for (int si = 0; si < nseg; si++) {
      seg_s[(size_t)b * MAXSEG + si] = bbL[si];
      seg_e[(size_t)b * MAXSEG + si] = bbL[si + 1];
    }
  }
}

// ---------------------------------------------------------------------------
// Stage 4: all DFT bins of all segments in parallel, table-free.
// Segment [s,e) owns flat bins [s/2, e/2), k = g - s/2 + 1. Twiddles advance
// by an in-register complex rotation along 4 interleaved j-chains (n is a
// multiple of 8). No scattered loads: agg[j] is wave-uniform (broadcast).
// fp contraction allowed here: only power magnitudes feed robust decisions.
// ---------------------------------------------------------------------------
__global__ __launch_bounds__(256) void k_bins(const double* __restrict__ agg,
                                              const int* __restrict__ bnd_g,
                                              const int* __restrict__ nbnd_g,
                                              double* __restrict__ segp) {
#pragma clang fp contract(fast)
  __shared__ int bbS[BNDCAP];
  int b = blockIdx.y;
  int nb = nbnd_g[b];
  for (int i = threadIdx.x; i < nb; i += 256) bbS[i] = bnd_g[(size_t)b * BNDCAP + i];
  __syncthreads();
  int g = blockIdx.x * 256 + threadIdx.x;  // 0..4095
  int pos = g * 2;
  int lo = 0, hi = nb - 1;
  while (hi - lo > 1) {
    int mid = (lo + hi) >> 1;
    if (bbS[mid] <= pos) lo = mid; else hi = mid;
  }
  int s = bbS[lo], e = bbS[lo + 1];
  int n = e - s;
  int k = g - s / 2 + 1;  // 1..n/2
  const double* ab = agg + (size_t)b * LL + s;
  const double twopi = 6.283185307179586;
  // step rotation for stride-4 chains
  int m4 = (4 * k) % n;
  double dth = twopi * ((double)m4 / (double)n);
  double cd = cos(dth), sd = sin(dth);
  // chain starts at j0 = 0..3: theta = 2*pi*((j0*k) mod n)/n
  double c0, s0c, c1, s1c, c2, s2c, c3, s3c;
  {
    int m1 = k % n, m2 = (2 * k) % n, m3 = (3 * k) % n;
    c0 = 1.0; s0c = 0.0;
    double t1 = twopi * ((double)m1 / (double)n);
    double t2 = twopi * ((double)m2 / (double)n);
    double t3 = twopi * ((double)m3 / (double)n);
    c1 = cos(t1); s1c = sin(t1);
    c2 = cos(t2); s2c = sin(t2);
    c3 = cos(t3); s3c = sin(t3);
  }
  double re0 = 0, re1 = 0, re2 = 0, re3 = 0;
  double im0 = 0, im1 = 0, im2 = 0, im3 = 0;
  int steps = n >> 2;  // n % 8 == 0 always
  for (int t = 0; t < steps; t++) {
    int j = t << 2;
    double a0 = ab[j + 0], a1 = ab[j + 1], a2 = ab[j + 2], a3 = ab[j + 3];
    re0 = re0 + a0 * c0; im0 = im0 + a0 * s0c;
    re1 = re1 + a1 * c1; im1 = im1 + a1 * s1c;
    re2 = re2 + a2 * c2; im2 = im2 + a2 * s2c;
    re3 = re3 + a3 * c3; im3 = im3 + a3 * s3c;
    double nc0 = c0 * cd - s0c * sd, ns0 = s0c * cd + c0 * sd;
    double nc1 = c1 * cd - s1c * sd, ns1 = s1c * cd + c1 * sd;
    double nc2 = c2 * cd - s2c * sd, ns2 = s2c * cd + c2 * sd;
    double nc3 = c3 * cd - s3c * sd, ns3 = s3c * cd + c3 * sd;
    c0 = nc0; s0c = ns0; c1 = nc1; s1c = ns1;
    c2 = nc2; s2c = ns2; c3 = nc3; s3c = ns3;
  }
  double re = (re0 + re1) + (re2 + re3);
  double im = (im0 + im1) + (im2 + im3);
  segp[(size_t)b * NBINS + g] = re * re + im * im;
}

// ---------------------------------------------------------------------------
// Stage 4c: per-segment stats from the flat power rows (staged in LDS),
// one thread per segment. Summation orders = numpy replica.
// ---------------------------------------------------------------------------
__global__ __launch_bounds__(256) void k_segfin(
    const double* __restrict__ segp, const int* __restrict__ seg_s,
    const int* __restrict__ seg_e, const int* __restrict__ nseg_g,
    int* __restrict__ seg_pl, double* __restrict__ seg_domp,
    double* __restrict__ seg_bw) {
  __shared__ double ppS[NBINS];  // 32 KB
  int b = blockIdx.x;
  for (int i = threadIdx.x; i < NBINS; i += 256) ppS[i] = segp[(size_t)b * NBINS + i];
  __syncthreads();
  int ns = nseg_g[b];
  for (int si = threadIdx.x; si < ns; si += 256) {
    int s = seg_s[(size_t)b * MAXSEG + si];
    int e = seg_e[(size_t)b * MAXSEG + si];
    int n = e - s;
    int nb2 = n / 2;
    int base = s / 2;
    double domp, bwv;
    if (n < 2) {
      domp = 1.0; bwv = 0.0;
    } else if (nb2 <= 1) {
      domp = (double)n; bwv = 0.0;
    } else {
      const double* pp = ppS + base;
      double sum = np_pairwise([&](int i) { return pp[i]; }, 0, nb2);
      double tot = (sum > 1e-8) ? sum : 1e-8;
      int dom = 0;
      double bv = pp[0];
      for (int i = 1; i < nb2; i++)
        if (pp[i] > bv) { bv = pp[i]; dom = i; }
      dom += 1;
      double spf = np_pairwise([&](int i) { return pp[i] * (double)(i + 1); }, 0, nb2);
      double cent = spf / tot;
      double sv = np_pairwise(
          [&](int i) {
            double d = (double)(i + 1) - cent;
            double dd = d * d;
            return dd * pp[i];
          },
          0, nb2);
      double var = sv / tot;
      bwv = sqrt(var > 0.0 ? var : 0.0) / (double)n;
      domp = (double)n / (double)dom;
    }
    double raw = (1.0 * domp) / (1.0 + 1.0 * bwv);
    int pl = (int)rint(raw / 2.0) * 2;  // Python round = half-to-even
    if (pl < 8) pl = 8;
    if (pl > 64) pl = 64;
    seg_pl[(size_t)b * MAXSEG + si] = pl;
    seg_domp[(size_t)b * MAXSEG + si] = domp;
    seg_bw[(size_t)b * MAXSEG + si] = bwv;
  }
}

// ---------------------------------------------------------------------------
// Stage 5: token enumeration (one thread per batch) + n_tokens output.
// ---------------------------------------------------------------------------
__global__ void k_tokens(const int* __restrict__ seg_s, const int* __restrict__ seg_e,
                         const int* __restrict__ seg_pl, const int* __restrict__ nseg_g,
                         int* __restrict__ tok_a, int* __restrict__ tok_z,
                         int* __restrict__ tok_sg, int* __restrict__ ntok_g,
                         float* __restrict__ out_nt) {
  int b = blockIdx.x * blockDim.x + threadIdx.x;
  if (b >= BB) return;
  int ns = nseg_g[b];
  int cnt = 0;
  for (int si = 0; si < ns; si++) {
    int s = seg_s[(size_t)b * MAXSEG + si];
    int e = seg_e[(size_t)b * MAXSEG + si];
    int pl = seg_pl[(size_t)b * MAXSEG + si];
    for (int a = s; a < e; a += pl) {
      int z = a + pl;
      if (z > e) z = e;
      tok_a[(size_t)b * MAXTOK + cnt] = a;
      tok_z[(size_t)b * MAXTOK + cnt] = z;
      tok_sg[(size_t)b * MAXTOK + cnt] = si;
      cnt++;
    }
  }
  ntok_g[b] = cnt;
  out_nt[b] = (float)cnt;
}

// ---------------------------------------------------------------------------
// Stage 6: per-token metadata outputs.
// ---------------------------------------------------------------------------
__global__ void k_tokfill(const int* __restrict__ tok_a, const int* __restrict__ tok_z,
                          const int* __restrict__ tok_sg, const int* __restrict__ ntok_g,
                          const int* __restrict__ seg_s, const int* __restrict__ seg_e,
                          const double* __restrict__ seg_domp,
                          const double* __restrict__ seg_bw, float* __restrict__ out,
                          int mx) {
  int b = blockIdx.x;
  int t = blockIdx.y * blockDim.x + threadIdx.x;
  if (t >= mx) return;
  if (t >= ntok_g[b]) return;
  size_t BM = (size_t)BB * (size_t)mx;
  float* mask = out + BM * 1024;
  float* start = mask + BM;
  float* endo = start + BM;
  float* cen = endo + BM;
  float* span = cen + BM;
  float* reg = span + BM;
  int a = tok_a[(size_t)b * MAXTOK + t];
  int z = tok_z[(size_t)b * MAXTOK + t];
  int si = tok_sg[(size_t)b * MAXTOK + t];
  size_t o = (size_t)b * (size_t)mx + t;
  mask[o] = 1.0f;
  start[o] = (float)a;
  endo[o] = (float)z;
  cen[o] = (float)(((double)(a + z - 1) * 0.5) / 8191.0);
  span[o] = (float)((double)(z - a) / 8192.0);
  int s = seg_s[(size_t)b * MAXSEG + si];
  int e = seg_e[(size_t)b * MAXSEG + si];
  reg[o * 3 + 0] = (float)(seg_domp[(size_t)b * MAXSEG + si] / 8192.0);
  reg[o * 3 + 1] = (float)seg_bw[(size_t)b * MAXSEG + si];
  reg[o * 3 + 2] = (float)((double)(e - s) / 8192.0);
}

// ---------------------------------------------------------------------------
// Stage 7: patch gather.
// ---------------------------------------------------------------------------
__global__ __launch_bounds__(256) void k_patches(const float* __restrict__ x,
                                                 const int* __restrict__ tok_a,
                                                 const int* __restrict__ tok_z,
                                                 const int* __restrict__ ntok_g,
                                                 float* __restrict__ out, int mx) {
  int t = blockIdx.x, b = blockIdx.y;
  if (t >= ntok_g[b]) return;
  __shared__ int g0[16], g1[16];
  __shared__ float wS[16];
  if (threadIdx.x < 16) {
    int a = tok_a[(size_t)b * MAXTOK + t];
    int z = tok_z[(size_t)b * MAXTOK + t];
    int n = z - a;
    double src = ((double)threadIdx.x + 0.5) * ((double)n / 16.0) - 0.5;
    if (src < 0.0) src = 0.0;
    double hi = (double)n - 1.0;
    if (src > hi) src = hi;
    double fi = floor(src);
    int i0 = (int)fi;
    int i1 = i0 + 1;
    if (i1 > n - 1) i1 = n - 1;
    g0[threadIdx.x] = a + i0;
    g1[threadIdx.x] = a + i1;
    wS[threadIdx.x] = (float)(src - fi);
  }
  __syncthreads();
  const float* xb = x + (size_t)b * CC * LL;
  float* ob = out + (((size_t)b * (size_t)mx + t) * CC) * 16;
  for (int e2 = threadIdx.x; e2 < CC * 16; e2 += 256) {
    int c = e2 >> 4, ai = e2 & 15;
    float wv = wS[ai];
    float v0 = xb[(size_t)c * LL + g0[ai]];
    float v1 = xb[(size_t)c * LL + g1[ai]];
    ob[e2] = v0 * (1.0f - wv) + v1 * wv;
  }
}

extern "C" void kernel_launch(void* const* d_in, const int* in_sizes, int n_in,
                              void* d_out, int out_size, void* d_ws, size_t ws_size,
                              hipStream_t stream) {
  (void)in_sizes; (void)n_in; (void)ws_size;
  const float* x = (const float*)d_in[0];
  float* out = (float*)d_out;
  // out_size = B*(1032*mx + 1)  -> recover mx
  long mx = ((long)out_size / BB - 1) / 1032;
  if (mx < 1) mx = 1;

  char* wp = (char*)d_ws;
  size_t off = 0;
  auto carve = [&](size_t bytes) -> void* {
    void* p = wp + off;
    off += (bytes + 255) & ~(size_t)255;
    return p;
  };
  double* agg = (double*)carve((size_t)BB * LL * 8);
  double* feat = (double*)carve((size_t)BB * NW * 3 * 8);
  double* segp = (double*)carve((size_t)BB * NBINS * 8);
  double* seg_domp = (double*)carve((size_t)BB * MAXSEG * 8);
  double* seg_bw = (double*)carve((size_t)BB * MAXSEG * 8);
  int* bnd = (int*)carve((size_t)BB * BNDCAP * 4);
  int* nbnd = (int*)carve((size_t)BB * 4);
  int* seg_s = (int*)carve((size_t)BB * MAXSEG * 4);
  int* seg_e = (int*)carve((size_t)BB * MAXSEG * 4);
  int* seg_pl = (int*)carve((size_t)BB * MAXSEG * 4);
  int* nseg = (int*)carve((size_t)BB * 4);
  int* tok_a = (int*)carve((size_t)BB * MAXTOK * 4);
  int* tok_z = (int*)carve((size_t)BB * MAXTOK * 4);
  int* tok_sg = (int*)carve((size_t)BB * MAXTOK * 4);
  int* ntok = (int*)carve((size_t)BB * 4);

  hipMemsetAsync(d_out, 0, (size_t)out_size * sizeof(float), stream);

  k_agg<<<(BB * LL + 255) / 256, 256, 0, stream>>>(x, agg);
  k_winfeat<<<(BB * NW + 255) / 256, 256, 0, stream>>>(agg, feat);
  k_dp<<<BB, 512, 0, stream>>>(feat, bnd, nbnd, seg_s, seg_e, nseg);
  dim3 gb(NBINS / 256, BB);
  k_bins<<<gb, 256, 0, stream>>>(agg, bnd, nbnd, segp);
  k_segfin<<<BB, 256, 0, stream>>>(segp, seg_s, seg_e, nseg, seg_pl, seg_domp,
                                   seg_bw);
  k_tokens<<<1, 64, 0, stream>>>(seg_s, seg_e, seg_pl, nseg, tok_a, tok_z,
                                 tok_sg, ntok, out + (size_t)BB * (size_t)mx * 1032);
  dim3 gf(BB, (unsigned)((mx + 255) / 256));
  k_tokfill<<<gf, 256, 0, stream>>>(tok_a, tok_z, tok_sg, ntok, seg_s, seg_e,
                                    seg_domp, seg_bw, out, (int)mx);
  dim3 gp((unsigned)mx, BB);
  k_patches<<<gp, 256, 0, stream>>>(x, tok_a, tok_z, ntok, out, (int)mx);
}

// Round 3
// 1398.822 us; speedup vs baseline: 1.1926x; 1.1926x over previous
//
#include <hip/hip_runtime.h>
#include <math.h>

#pragma clang fp contract(off)

#define BB 32
#define CC 64
#define LL 8192
#define NW 1021      // number of spectral windows: (8192-32)/8 + 1
#define MAXSEG 1024
#define MAXTOK 1024
#define BNDCAP 1026
#define NBINS (LL / 2)   // 4096 flat bins per batch (segments partition [0,L))

// DP blocking parameters
#define DP_T 64          // ends per block
#define DP_NBLK 16       // ceil(NW / DP_T)
#define DP_NWAVE 16      // waves per workgroup (1024 threads)
#define DP_MARGIN 1e-6   // approx->exact trigger margin; approx err <= ~1e-11

// ---------------------------------------------------------------------------
// numpy pairwise_sum replica (loops.c.src): n<8 sequential, n<=128 blocked with
// 8 accumulators, else recursive halving with n2 -= n2 % 8.
// ---------------------------------------------------------------------------
template <typename F>
__device__ double np_pairwise(const F& f, int off, int n) {
  if (n < 8) {
    double res = 0.0;
    for (int i = 0; i < n; i++) res = res + f(off + i);
    return res;
  }
  if (n <= 128) {
    double r0 = f(off + 0), r1 = f(off + 1), r2 = f(off + 2), r3 = f(off + 3);
    double r4 = f(off + 4), r5 = f(off + 5), r6 = f(off + 6), r7 = f(off + 7);
    int i = 8;
    int lim = n - (n % 8);
    for (; i < lim; i += 8) {
      r0 = r0 + f(off + i + 0); r1 = r1 + f(off + i + 1);
      r2 = r2 + f(off + i + 2); r3 = r3 + f(off + i + 3);
      r4 = r4 + f(off + i + 4); r5 = r5 + f(off + i + 5);
      r6 = r6 + f(off + i + 6); r7 = r7 + f(off + i + 7);
    }
    double res = ((r0 + r1) + (r2 + r3)) + ((r4 + r5) + (r6 + r7));
    for (; i < n; i++) res = res + f(off + i);
    return res;
  }
  int n2 = n / 2;
  n2 -= n2 % 8;
  return np_pairwise(f, off, n2) + np_pairwise(f, off + n2, n - n2);
}

// ---------------------------------------------------------------------------
// Stage 1: agg[b][l] = channel mean, numpy sequential f32 order.
// ---------------------------------------------------------------------------
__global__ void k_agg(const float* __restrict__ x, double* __restrict__ agg) {
  int idx = blockIdx.x * blockDim.x + threadIdx.x;
  if (idx >= BB * LL) return;
  int b = idx / LL, l = idx - b * LL;
  const float* xb = x + (size_t)b * CC * LL + l;
  float s = 0.0f;
  for (int c = 0; c < CC; c++) s = s + xb[(size_t)c * LL];
  agg[idx] = (double)(s / 64.0f);
}

// ---------------------------------------------------------------------------
// Stage 2: per-window spectral features (32-pt DFT, bins 1..16).
// ---------------------------------------------------------------------------
__global__ void k_winfeat(const double* __restrict__ agg, double* __restrict__ feat) {
  __shared__ double tc[32], tsn[32];
  if (threadIdx.x < 32) {
    double th = 6.283185307179586 * ((double)threadIdx.x / 32.0);
    tc[threadIdx.x] = cos(th);
    tsn[threadIdx.x] = sin(th);
  }
  __syncthreads();
  int idx = blockIdx.x * blockDim.x + threadIdx.x;
  if (idx >= BB * NW) return;
  int b = idx / NW, w = idx - b * NW;
  const double* a = agg + (size_t)b * LL + (size_t)w * 8;
  double av[32];
#pragma unroll
  for (int t = 0; t < 32; t++) av[t] = a[t];
  double p[16];
  for (int k = 1; k <= 16; k++) {
    double re = 0.0, im = 0.0;
    int m = 0;
    for (int t = 0; t < 32; t++) {
      re = re + av[t] * tc[m];
      im = im + av[t] * tsn[m];
      m = (m + k) & 31;
    }
    p[k - 1] = re * re + im * im;
  }
  double r[8];
  for (int i = 0; i < 8; i++) r[i] = p[i] + p[i + 8];
  double sum = ((r[0] + r[1]) + (r[2] + r[3])) + ((r[4] + r[5]) + (r[6] + r[7]));
  double tot = (sum > 1e-8) ? sum : 1e-8;
  double pf[16];
  for (int i = 0; i < 16; i++) pf[i] = p[i] * (double)(i + 1);
  for (int i = 0; i < 8; i++) r[i] = pf[i] + pf[i + 8];
  double spf = ((r[0] + r[1]) + (r[2] + r[3])) + ((r[4] + r[5]) + (r[6] + r[7]));
  int dom = 0;
  double bv = p[0];
  for (int i = 1; i < 16; i++)
    if (p[i] > bv) { bv = p[i]; dom = i; }
  dom += 1;
  double cent = spf / tot;
  double q[16];
  for (int i = 0; i < 16; i++) {
    double d = (double)(i + 1) - cent;
    double dd = d * d;
    q[i] = dd * p[i];
  }
  for (int i = 0; i < 8; i++) r[i] = q[i] + q[i + 8];
  double sv = ((r[0] + r[1]) + (r[2] + r[3])) + ((r[4] + r[5]) + (r[6] + r[7]));
  double var = sv / tot;
  double bw = sqrt(var > 0.0 ? var : 0.0) / 32.0;
  double mean = sum / 16.0;
  double* f = feat + ((size_t)b * NW + (size_t)w) * 3;
  f[0] = (double)dom / 32.0;
  f[1] = bw;
  f[2] = log1p(mean);
}

// ---------------------------------------------------------------------------
// Stage 3: PELT DP, blocked, two-tier exact evaluation.
//  * cmb[j] = {p0,p1,p2,q0,q1,q2,dp,pad}: one 64B record per j -> wave-uniform
//    broadcast loads collapse to 3x ds_read_b128 + 1x b64 per candidate.
//  * Phase A (all 16 waves): candidate screened with u * invL[sl] (3 muls,
//    invL = correctly-rounded 1/sl table). Exact 3-divide path only when
//    approx <= running_approx_min + MARGIN. Bound: |approx-exact| <= ~1e-11
//    << MARGIN, so every exact-min candidate (incl. all ties) IS exact-
//    evaluated, and non-triggered candidates are strictly worse: dp values,
//    argmins, first-occurrence ties bit-identical to the all-exact scan.
//  * Phase B (wave 0): serial 64-step chain over the precomputed sse
//    triangle; waves 1..15 concurrently precompute the NEXT block's triangle
//    (dp-independent) into the other sseT buffer.
// ---------------------------------------------------------------------------
__global__ __launch_bounds__(1024) void k_dp(const double* __restrict__ feat,
                                             int* __restrict__ bnd_g,
                                             int* __restrict__ nbnd_g,
                                             int* __restrict__ seg_s,
                                             int* __restrict__ seg_e,
                                             int* __restrict__ nseg_g) {
  __shared__ double cmb[NW + 1][8];            // 65,408 B
  __shared__ double sseT[2][DP_T][DP_T + 1];   // 66,560 B (buf0 = feat staging)
  __shared__ double pvL[DP_T][DP_NWAVE + 1];   // 8,704 B
  __shared__ int pixL[DP_T][DP_NWAVE + 1];     // 4,352 B
  __shared__ int prevL[NW + 1];                // 4,088 B
  __shared__ double invL[NW + 1];              // 8,176 B   (total ~157 KB)
  int b = blockIdx.x;
  int tid = threadIdx.x;
  const double* fb = feat + (size_t)b * NW * 3;

  // Stage feat into LDS (coalesced), build 1/sl table, init cmb[0].
  double* featS = &sseT[0][0][0];  // 4160 doubles >= NW*3 = 3063
  for (int i = tid; i < NW * 3; i += 1024) featS[i] = fb[i];
  for (int i = tid + 1; i <= NW; i += 1024) invL[i] = 1.0 / (double)i;
  if (tid == 0) {
    cmb[0][0] = 0.0; cmb[0][1] = 0.0; cmb[0][2] = 0.0;
    cmb[0][3] = 0.0; cmb[0][4] = 0.0; cmb[0][5] = 0.0;
    cmb[0][6] = -1.0;  // dp[0] = -penalty
  }
  __syncthreads();

  // 6 independent sequential prefix chains (3 ch x {sum, sumsq}); per-channel
  // accumulation order identical to np.cumsum -> bit-exact.
  if (tid < 6) {
    int c = tid % 3;
    bool sq = tid >= 3;
    int col = sq ? 3 + c : c;
    double acc = 0.0;
    for (int i = 0; i < NW; i++) {
      double f = featS[i * 3 + c];
      double v = sq ? f * f : f;
      acc = acc + v;
      cmb[i + 1][col] = acc;
    }
  }
  __syncthreads();

  int lane = tid & 63;   // end offset within block
  int w = tid >> 6;      // wave id 0..15

  // Prologue: triangle for block 0 into sseT[0] (featS fully consumed above).
  {
    int end = 1 + lane;
    double pe0 = cmb[end][0], pe1 = cmb[end][1], pe2 = cmb[end][2];
    double qe0 = cmb[end][3], qe1 = cmb[end][4], qe2 = cmb[end][5];
    for (int s = w; s < DP_T; s += DP_NWAVE) {
      int j = s;
      double sl = (double)(end - j);
      double s0 = pe0 - cmb[j][0], s1 = pe1 - cmb[j][1], s2 = pe2 - cmb[j][2];
      double u0 = s0 * s0, u1 = s1 * s1, u2 = s2 * s2;
      double t0 = (qe0 - cmb[j][3]) - u0 / sl;
      double t1 = (qe1 - cmb[j][4]) - u1 / sl;
      double t2 = (qe2 - cmb[j][5]) - u2 / sl;
      sseT[0][s][lane] = (t0 + t1) + t2;
    }
  }
  __syncthreads();

  double dpLast = -1.0;  // dp[e0] seen by wave 0 at phase-B entry (dp[0] = -1)

  for (int blk = 0; blk < DP_NBLK; blk++) {
    int cur = blk & 1, nxt = cur ^ 1;
    int e0 = blk * DP_T;
    int ecnt = NW - e0;
    if (ecnt > DP_T) ecnt = DP_T;
    int end = e0 + 1 + lane;
    if (end > NW) end = NW;  // clamp; writes are guarded by lane==s<ecnt
    double pe0 = cmb[end][0], pe1 = cmb[end][1], pe2 = cmb[end][2];
    double qe0 = cmb[end][3], qe1 = cmb[end][4], qe2 = cmb[end][5];
    double v = __builtin_inf();
    int ix = 0;
    double vminA = __builtin_inf();
    // Phase A: j in residue class w, ascending. Approx screen + exact trigger.
    for (int j = w; j < e0; j += DP_NWAVE) {
      double p0 = cmb[j][0], p1 = cmb[j][1], p2 = cmb[j][2];
      double q0 = cmb[j][3], q1 = cmb[j][4], q2 = cmb[j][5];
      double dpj = cmb[j][6];
      int sli = end - j;
      double inv = invL[sli];
      double s0 = pe0 - p0, s1 = pe1 - p1, s2 = pe2 - p2;
      double u0 = s0 * s0, u1 = s1 * s1, u2 = s2 * s2;
      double d0 = qe0 - q0, d1 = qe1 - q1, d2 = qe2 - q2;
      double ta0 = d0 - u0 * inv, ta1 = d1 - u1 * inv, ta2 = d2 - u2 * inv;
      double candA = (dpj + ((ta0 + ta1) + ta2)) + 1.0;
      if (candA <= vminA + DP_MARGIN) {
        double sl = (double)sli;
        double t0 = d0 - u0 / sl, t1 = d1 - u1 / sl, t2 = d2 - u2 / sl;
        double cand = (dpj + ((t0 + t1) + t2)) + 1.0;
        if (cand < v || (cand == v && j < ix)) { v = cand; ix = j; }
      }
      if (candA < vminA) vminA = candA;
    }
    pvL[lane][w] = v;
    pixL[lane][w] = ix;
    __syncthreads();
    if (w == 0) {
      // Merge wave partials: global first-occurrence argmin via ix tie-break.
      double vcur = pvL[lane][0];
      int ixcur = pixL[lane][0];
#pragma unroll
      for (int t = 1; t < DP_NWAVE; t++) {
        double ov = pvL[lane][t];
        int oi = pixL[lane][t];
        if (ov < vcur || (ov == vcur && oi < ixcur)) { vcur = ov; ixcur = oi; }
      }
      // Phase B: serial chain; sse precomputed, load double-buffered 1 ahead.
      double sse_next = sseT[cur][0][lane];
      for (int s = 0; s < ecnt; s++) {
        double sse_cur = sse_next;
        if (s + 1 < ecnt) sse_next = sseT[cur][s + 1][lane];
        double dpj = (s == 0) ? dpLast : __shfl(vcur, s - 1, 64);
        double cand = (dpj + sse_cur) + 1.0;
        if (lane >= s && cand < vcur) { vcur = cand; ixcur = e0 + s; }
        if (lane == s) {
          cmb[end][6] = vcur;
          prevL[end] = ixcur;
        }
      }
      dpLast = __shfl(vcur, ecnt - 1, 64);  // dp[e0 + ecnt] for next block
    } else if (blk + 1 < DP_NBLK) {
      // Waves 1..15: precompute next block's triangle (dp-independent).
      int e0n = e0 + DP_T;
      int ecn = NW - e0n;
      if (ecn > DP_T) ecn = DP_T;
      int endn = e0n + 1 + lane;
      if (endn > NW) endn = NW;
      double pn0 = cmb[endn][0], pn1 = cmb[endn][1], pn2 = cmb[endn][2];
      double qn0 = cmb[endn][3], qn1 = cmb[endn][4], qn2 = cmb[endn][5];
      for (int s = w - 1; s < ecn; s += DP_NWAVE - 1) {
        int j = e0n + s;
        double sl = (double)(endn - j);
        double s0 = pn0 - cmb[j][0], s1 = pn1 - cmb[j][1], s2 = pn2 - cmb[j][2];
        double u0 = s0 * s0, u1 = s1 * s1, u2 = s2 * s2;
        double t0 = (qn0 - cmb[j][3]) - u0 / sl;
        double t1 = (qn1 - cmb[j][4]) - u1 / sl;
        double t2 = (qn2 - cmb[j][5]) - u2 / sl;
        sseT[nxt][s][lane] = (t0 + t1) + t2;
      }
    }
    __syncthreads();
  }

  if (tid == 0) {
    int* chain = (int*)cmb;   // reuse LDS (cmb no longer needed)
    int cnt = 0, i = NW;
    while (i > 0) { i = prevL[i]; chain[cnt++] = i; }
    int* bbL = (int*)invL;    // reuse LDS (1026 ints fit in 8176 B)
    int nb = 0;
    bbL[nb++] = 0;
    for (int t = cnt - 2; t >= 0; t--) {  // interior breakpoints, ascending
      int w2 = chain[t];
      int tt = w2 * 8;
      if (tt <= bbL[nb - 1]) continue;
      if (tt - bbL[nb - 1] < 8) continue;
      if (LL - tt < 8) continue;
      bbL[nb++] = tt;
    }
    bbL[nb++] = LL;
    int* bb = bnd_g + (size_t)b * BNDCAP;
    for (int t = 0; t < nb; t++) bb[t] = bbL[t];
    nbnd_g[b] = nb;
    int nseg = nb - 1;
    nseg_g[b] = nseg;
    for (int si = 0; si < nseg; si++) {
      seg_s[(size_t)b * MAXSEG + si] = bbL[si];
      seg_e[(size_t)b * MAXSEG + si] = bbL[si + 1];
    }
  }
}

// ---------------------------------------------------------------------------
// Stage 4: all DFT bins of all segments in parallel, table-free.
// ---------------------------------------------------------------------------
__global__ __launch_bounds__(256) void k_bins(const double* __restrict__ agg,
                                              const int* __restrict__ bnd_g,
                                              const int* __restrict__ nbnd_g,
                                              double* __restrict__ segp) {
#pragma clang fp contract(fast)
  __shared__ int bbS[BNDCAP];
  int b = blockIdx.y;
  int nb = nbnd_g[b];
  for (int i = threadIdx.x; i < nb; i += 256) bbS[i] = bnd_g[(size_t)b * BNDCAP + i];
  __syncthreads();
  int g = blockIdx.x * 256 + threadIdx.x;  // 0..4095
  int pos = g * 2;
  int lo = 0, hi = nb - 1;
  while (hi - lo > 1) {
    int mid = (lo + hi) >> 1;
    if (bbS[mid] <= pos) lo = mid; else hi = mid;
  }
  int s = bbS[lo], e = bbS[lo + 1];
  int n = e - s;
  int k = g - s / 2 + 1;  // 1..n/2
  const double* ab = agg + (size_t)b * LL + s;
  const double twopi = 6.283185307179586;
  int m4 = (4 * k) % n;
  double dth = twopi * ((double)m4 / (double)n);
  double cd = cos(dth), sd = sin(dth);
  double c0, s0c, c1, s1c, c2, s2c, c3, s3c;
  {
    int m1 = k % n, m2 = (2 * k) % n, m3 = (3 * k) % n;
    c0 = 1.0; s0c = 0.0;
    double t1 = twopi * ((double)m1 / (double)n);
    double t2 = twopi * ((double)m2 / (double)n);
    double t3 = twopi * ((double)m3 / (double)n);
    c1 = cos(t1); s1c = sin(t1);
    c2 = cos(t2); s2c = sin(t2);
    c3 = cos(t3); s3c = sin(t3);
  }
  double re0 = 0, re1 = 0, re2 = 0, re3 = 0;
  double im0 = 0, im1 = 0, im2 = 0, im3 = 0;
  int steps = n >> 2;  // n % 8 == 0 always
  for (int t = 0; t < steps; t++) {
    int j = t << 2;
    double a0 = ab[j + 0], a1 = ab[j + 1], a2 = ab[j + 2], a3 = ab[j + 3];
    re0 = re0 + a0 * c0; im0 = im0 + a0 * s0c;
    re1 = re1 + a1 * c1; im1 = im1 + a1 * s1c;
    re2 = re2 + a2 * c2; im2 = im2 + a2 * s2c;
    re3 = re3 + a3 * c3; im3 = im3 + a3 * s3c;
    double nc0 = c0 * cd - s0c * sd, ns0 = s0c * cd + c0 * sd;
    double nc1 = c1 * cd - s1c * sd, ns1 = s1c * cd + c1 * sd;
    double nc2 = c2 * cd - s2c * sd, ns2 = s2c * cd + c2 * sd;
    double nc3 = c3 * cd - s3c * sd, ns3 = s3c * cd + c3 * sd;
    c0 = nc0; s0c = ns0; c1 = nc1; s1c = ns1;
    c2 = nc2; s2c = ns2; c3 = nc3; s3c = ns3;
  }
  double re = (re0 + re1) + (re2 + re3);
  double im = (im0 + im1) + (im2 + im3);
  segp[(size_t)b * NBINS + g] = re * re + im * im;
}

// ---------------------------------------------------------------------------
// Stage 4c: per-segment stats from the flat power rows (staged in LDS).
// ---------------------------------------------------------------------------
__global__ __launch_bounds__(256) void k_segfin(
    const double* __restrict__ segp, const int* __restrict__ seg_s,
    const int* __restrict__ seg_e, const int* __restrict__ nseg_g,
    int* __restrict__ seg_pl, double* __restrict__ seg_domp,
    double* __restrict__ seg_bw) {
  __shared__ double ppS[NBINS];  // 32 KB
  int b = blockIdx.x;
  for (int i = threadIdx.x; i < NBINS; i += 256) ppS[i] = segp[(size_t)b * NBINS + i];
  __syncthreads();
  int ns = nseg_g[b];
  for (int si = threadIdx.x; si < ns; si += 256) {
    int s = seg_s[(size_t)b * MAXSEG + si];
    int e = seg_e[(size_t)b * MAXSEG + si];
    int n = e - s;
    int nb2 = n / 2;
    int base = s / 2;
    double domp, bwv;
    if (n < 2) {
      domp = 1.0; bwv = 0.0;
    } else if (nb2 <= 1) {
      domp = (double)n; bwv = 0.0;
    } else {
      const double* pp = ppS + base;
      double sum = np_pairwise([&](int i) { return pp[i]; }, 0, nb2);
      double tot = (sum > 1e-8) ? sum : 1e-8;
      int dom = 0;
      double bv = pp[0];
      for (int i = 1; i < nb2; i++)
        if (pp[i] > bv) { bv = pp[i]; dom = i; }
      dom += 1;
      double spf = np_pairwise([&](int i) { return pp[i] * (double)(i + 1); }, 0, nb2);
      double cent = spf / tot;
      double sv = np_pairwise(
          [&](int i) {
            double d = (double)(i + 1) - cent;
            double dd = d * d;
            return dd * pp[i];
          },
          0, nb2);
      double var = sv / tot;
      bwv = sqrt(var > 0.0 ? var : 0.0) / (double)n;
      domp = (double)n / (double)dom;
    }
    double raw = (1.0 * domp) / (1.0 + 1.0 * bwv);
    int pl = (int)rint(raw / 2.0) * 2;  // Python round = half-to-even
    if (pl < 8) pl = 8;
    if (pl > 64) pl = 64;
    seg_pl[(size_t)b * MAXSEG + si] = pl;
    seg_domp[(size_t)b * MAXSEG + si] = domp;
    seg_bw[(size_t)b * MAXSEG + si] = bwv;
  }
}

// ---------------------------------------------------------------------------
// Stage 5: token enumeration (one thread per batch) + n_tokens output.
// ---------------------------------------------------------------------------
__global__ void k_tokens(const int* __restrict__ seg_s, const int* __restrict__ seg_e,
                         const int* __restrict__ seg_pl, const int* __restrict__ nseg_g,
                         int* __restrict__ tok_a, int* __restrict__ tok_z,
                         int* __restrict__ tok_sg, int* __restrict__ ntok_g,
                         float* __restrict__ out_nt) {
  int b = blockIdx.x * blockDim.x + threadIdx.x;
  if (b >= BB) return;
  int ns = nseg_g[b];
  int cnt = 0;
  for (int si = 0; si < ns; si++) {
    int s = seg_s[(size_t)b * MAXSEG + si];
    int e = seg_e[(size_t)b * MAXSEG + si];
    int pl = seg_pl[(size_t)b * MAXSEG + si];
    for (int a = s; a < e; a += pl) {
      int z = a + pl;
      if (z > e) z = e;
      tok_a[(size_t)b * MAXTOK + cnt] = a;
      tok_z[(size_t)b * MAXTOK + cnt] = z;
      tok_sg[(size_t)b * MAXTOK + cnt] = si;
      cnt++;
    }
  }
  ntok_g[b] = cnt;
  out_nt[b] = (float)cnt;
}

// ---------------------------------------------------------------------------
// Stage 6: per-token metadata outputs. Padded tokens (t >= ntok) are
// zero-filled here (the big output memset is gone).
// ---------------------------------------------------------------------------
__global__ void k_tokfill(const int* __restrict__ tok_a, const int* __restrict__ tok_z,
                          const int* __restrict__ tok_sg, const int* __restrict__ ntok_g,
                          const int* __restrict__ seg_s, const int* __restrict__ seg_e,
                          const double* __restrict__ seg_domp,
                          const double* __restrict__ seg_bw, float* __restrict__ out,
                          int mx) {
  int b = blockIdx.x;
  int t = blockIdx.y * blockDim.x + threadIdx.x;
  if (t >= mx) return;
  size_t BM = (size_t)BB * (size_t)mx;
  float* mask = out + BM * 1024;
  float* start = mask + BM;
  float* endo = start + BM;
  float* cen = endo + BM;
  float* span = cen + BM;
  float* reg = span + BM;
  size_t o = (size_t)b * (size_t)mx + t;
  if (t >= ntok_g[b]) {
    mask[o] = 0.0f; start[o] = 0.0f; endo[o] = 0.0f;
    cen[o] = 0.0f; span[o] = 0.0f;
    reg[o * 3 + 0] = 0.0f; reg[o * 3 + 1] = 0.0f; reg[o * 3 + 2] = 0.0f;
    return;
  }
  int a = tok_a[(size_t)b * MAXTOK + t];
  int z = tok_z[(size_t)b * MAXTOK + t];
  int si = tok_sg[(size_t)b * MAXTOK + t];
  mask[o] = 1.0f;
  start[o] = (float)a;
  endo[o] = (float)z;
  cen[o] = (float)(((double)(a + z - 1) * 0.5) / 8191.0);
  span[o] = (float)((double)(z - a) / 8192.0);
  int s = seg_s[(size_t)b * MAXSEG + si];
  int e = seg_e[(size_t)b * MAXSEG + si];
  reg[o * 3 + 0] = (float)(seg_domp[(size_t)b * MAXSEG + si] / 8192.0);
  reg[o * 3 + 1] = (float)seg_bw[(size_t)b * MAXSEG + si];
  reg[o * 3 + 2] = (float)((double)(e - s) / 8192.0);
}

// ---------------------------------------------------------------------------
// Stage 7: patch gather. Padded tokens are zero-filled (memset removed).
// ---------------------------------------------------------------------------
__global__ __launch_bounds__(256) void k_patches(const float* __restrict__ x,
                                                 const int* __restrict__ tok_a,
                                                 const int* __restrict__ tok_z,
                                                 const int* __restrict__ ntok_g,
                                                 float* __restrict__ out, int mx) {
  int t = blockIdx.x, b = blockIdx.y;
  float* ob = out + (((size_t)b * (size_t)mx + t) * CC) * 16;
  if (t >= ntok_g[b]) {
    for (int e2 = threadIdx.x; e2 < CC * 16; e2 += 256) ob[e2] = 0.0f;
    return;
  }
  __shared__ int g0[16], g1[16];
  __shared__ float wS[16];
  if (threadIdx.x < 16) {
    int a = tok_a[(size_t)b * MAXTOK + t];
    int z = tok_z[(size_t)b * MAXTOK + t];
    int n = z - a;
    double src = ((double)threadIdx.x + 0.5) * ((double)n / 16.0) - 0.5;
    if (src < 0.0) src = 0.0;
    double hi = (double)n - 1.0;
    if (src > hi) src = hi;
    double fi = floor(src);
    int i0 = (int)fi;
    int i1 = i0 + 1;
    if (i1 > n - 1) i1 = n - 1;
    g0[threadIdx.x] = a + i0;
    g1[threadIdx.x] = a + i1;
    wS[threadIdx.x] = (float)(src - fi);
  }
  __syncthreads();
  const float* xb = x + (size_t)b * CC * LL;
  for (int e2 = threadIdx.x; e2 < CC * 16; e2 += 256) {
    int c = e2 >> 4, ai = e2 & 15;
    float wv = wS[ai];
    float v0 = xb[(size_t)c * LL + g0[ai]];
    float v1 = xb[(size_t)c * LL + g1[ai]];
    ob[e2] = v0 * (1.0f - wv) + v1 * wv;
  }
}

extern "C" void kernel_launch(void* const* d_in, const int* in_sizes, int n_in,
                              void* d_out, int out_size, void* d_ws, size_t ws_size,
                              hipStream_t stream) {
  (void)in_sizes; (void)n_in; (void)ws_size;
  const float* x = (const float*)d_in[0];
  float* out = (float*)d_out;
  // out_size = B*(1032*mx + 1)  -> recover mx
  long mx = ((long)out_size / BB - 1) / 1032;
  if (mx < 1) mx = 1;

  char* wp = (char*)d_ws;
  size_t off = 0;
  auto carve = [&](size_t bytes) -> void* {
    void* p = wp + off;
    off += (bytes + 255) & ~(size_t)255;
    return p;
  };
  double* agg = (double*)carve((size_t)BB * LL * 8);
  double* feat = (double*)carve((size_t)BB * NW * 3 * 8);
  double* segp = (double*)carve((size_t)BB * NBINS * 8);
  double* seg_domp = (double*)carve((size_t)BB * MAXSEG * 8);
  double* seg_bw = (double*)carve((size_t)BB * MAXSEG * 8);
  int* bnd = (int*)carve((size_t)BB * BNDCAP * 4);
  int* nbnd = (int*)carve((size_t)BB * 4);
  int* seg_s = (int*)carve((size_t)BB * MAXSEG * 4);
  int* seg_e = (int*)carve((size_t)BB * MAXSEG * 4);
  int* seg_pl = (int*)carve((size_t)BB * MAXSEG * 4);
  int* nseg = (int*)carve((size_t)BB * 4);
  int* tok_a = (int*)carve((size_t)BB * MAXTOK * 4);
  int* tok_z = (int*)carve((size_t)BB * MAXTOK * 4);
  int* tok_sg = (int*)carve((size_t)BB * MAXTOK * 4);
  int* ntok = (int*)carve((size_t)BB * 4);

  k_agg<<<(BB * LL + 255) / 256, 256, 0, stream>>>(x, agg);
  k_winfeat<<<(BB * NW + 255) / 256, 256, 0, stream>>>(agg, feat);
  k_dp<<<BB, 1024, 0, stream>>>(feat, bnd, nbnd, seg_s, seg_e, nseg);
  dim3 gb(NBINS / 256, BB);
  k_bins<<<gb, 256, 0, stream>>>(agg, bnd, nbnd, segp);
  k_segfin<<<BB, 256, 0, stream>>>(segp, seg_s, seg_e, nseg, seg_pl, seg_domp,
                                   seg_bw);
  k_tokens<<<1, 64, 0, stream>>>(seg_s, seg_e, seg_pl, nseg, tok_a, tok_z,
                                 tok_sg, ntok, out + (size_t)BB * (size_t)mx * 1032);
  dim3 gf(BB, (unsigned)((mx + 255) / 256));
  k_tokfill<<<gf, 256, 0, stream>>>(tok_a, tok_z, tok_sg, ntok, seg_s, seg_e,
                                    seg_domp, seg_bw, out, (int)mx);
  dim3 gp((unsigned)mx, BB);
  k_patches<<<gp, 256, 0, stream>>>(x, tok_a, tok_z, ntok, out, (int)mx);
}

// Round 4
// 1249.559 us; speedup vs baseline: 1.3351x; 1.1195x over previous
//
#include <hip/hip_runtime.h>
#include <math.h>

#pragma clang fp contract(off)

#define BB 32
#define CC 64
#define LL 8192
#define NW 1021      // number of spectral windows: (8192-32)/8 + 1
#define MAXSEG 1024
#define MAXTOK 1024
#define BNDCAP 1026
#define NBINS (LL / 2)   // 4096 flat bins per batch (segments partition [0,L))

// DP blocking parameters
#define DP_T 64          // ends per block
#define DP_NBLK 16       // ceil(NW / DP_T)
#define DP_NWAVE 16      // waves per workgroup (1024 threads)
#define DP_MARGIN 1e-6   // approx->exact trigger margin; approx err <= ~1e-11

// ---------------------------------------------------------------------------
// numpy pairwise_sum replica (loops.c.src): n<8 sequential, n<=128 blocked with
// 8 accumulators, else recursive halving with n2 -= n2 % 8.
// ---------------------------------------------------------------------------
template <typename F>
__device__ double np_pairwise(const F& f, int off, int n) {
  if (n < 8) {
    double res = 0.0;
    for (int i = 0; i < n; i++) res = res + f(off + i);
    return res;
  }
  if (n <= 128) {
    double r0 = f(off + 0), r1 = f(off + 1), r2 = f(off + 2), r3 = f(off + 3);
    double r4 = f(off + 4), r5 = f(off + 5), r6 = f(off + 6), r7 = f(off + 7);
    int i = 8;
    int lim = n - (n % 8);
    for (; i < lim; i += 8) {
      r0 = r0 + f(off + i + 0); r1 = r1 + f(off + i + 1);
      r2 = r2 + f(off + i + 2); r3 = r3 + f(off + i + 3);
      r4 = r4 + f(off + i + 4); r5 = r5 + f(off + i + 5);
      r6 = r6 + f(off + i + 6); r7 = r7 + f(off + i + 7);
    }
    double res = ((r0 + r1) + (r2 + r3)) + ((r4 + r5) + (r6 + r7));
    for (; i < n; i++) res = res + f(off + i);
    return res;
  }
  int n2 = n / 2;
  n2 -= n2 % 8;
  return np_pairwise(f, off, n2) + np_pairwise(f, off + n2, n - n2);
}

// ---------------------------------------------------------------------------
// Stage 1: agg[b][l] = channel mean, numpy sequential f32 order.
// ---------------------------------------------------------------------------
__global__ void k_agg(const float* __restrict__ x, double* __restrict__ agg) {
  int idx = blockIdx.x * blockDim.x + threadIdx.x;
  if (idx >= BB * LL) return;
  int b = idx / LL, l = idx - b * LL;
  const float* xb = x + (size_t)b * CC * LL + l;
  float s = 0.0f;
  for (int c = 0; c < CC; c++) s = s + xb[(size_t)c * LL];
  agg[idx] = (double)(s / 64.0f);
}

// ---------------------------------------------------------------------------
// Stage 2: per-window spectral features (32-pt DFT, bins 1..16).
// ---------------------------------------------------------------------------
__global__ void k_winfeat(const double* __restrict__ agg, double* __restrict__ feat) {
  __shared__ double tc[32], tsn[32];
  if (threadIdx.x < 32) {
    double th = 6.283185307179586 * ((double)threadIdx.x / 32.0);
    tc[threadIdx.x] = cos(th);
    tsn[threadIdx.x] = sin(th);
  }
  __syncthreads();
  int idx = blockIdx.x * blockDim.x + threadIdx.x;
  if (idx >= BB * NW) return;
  int b = idx / NW, w = idx - b * NW;
  const double* a = agg + (size_t)b * LL + (size_t)w * 8;
  double av[32];
#pragma unroll
  for (int t = 0; t < 32; t++) av[t] = a[t];
  double p[16];
  for (int k = 1; k <= 16; k++) {
    double re = 0.0, im = 0.0;
    int m = 0;
    for (int t = 0; t < 32; t++) {
      re = re + av[t] * tc[m];
      im = im + av[t] * tsn[m];
      m = (m + k) & 31;
    }
    p[k - 1] = re * re + im * im;
  }
  double r[8];
  for (int i = 0; i < 8; i++) r[i] = p[i] + p[i + 8];
  double sum = ((r[0] + r[1]) + (r[2] + r[3])) + ((r[4] + r[5]) + (r[6] + r[7]));
  double tot = (sum > 1e-8) ? sum : 1e-8;
  double pf[16];
  for (int i = 0; i < 16; i++) pf[i] = p[i] * (double)(i + 1);
  for (int i = 0; i < 8; i++) r[i] = pf[i] + pf[i + 8];
  double spf = ((r[0] + r[1]) + (r[2] + r[3])) + ((r[4] + r[5]) + (r[6] + r[7]));
  int dom = 0;
  double bv = p[0];
  for (int i = 1; i < 16; i++)
    if (p[i] > bv) { bv = p[i]; dom = i; }
  dom += 1;
  double cent = spf / tot;
  double q[16];
  for (int i = 0; i < 16; i++) {
    double d = (double)(i + 1) - cent;
    double dd = d * d;
    q[i] = dd * p[i];
  }
  for (int i = 0; i < 8; i++) r[i] = q[i] + q[i + 8];
  double sv = ((r[0] + r[1]) + (r[2] + r[3])) + ((r[4] + r[5]) + (r[6] + r[7]));
  double var = sv / tot;
  double bw = sqrt(var > 0.0 ? var : 0.0) / 32.0;
  double mean = sum / 16.0;
  double* f = feat + ((size_t)b * NW + (size_t)w) * 3;
  f[0] = (double)dom / 32.0;
  f[1] = bw;
  f[2] = log1p(mean);
}

// ---------------------------------------------------------------------------
// Stage 3: PELT DP, blocked, two-tier exact evaluation.
//  * cmb[j] = {p0,p1,p2,q0,q1,q2,dp,pad}: one 64B record per j -> wave-uniform
//    broadcast loads collapse to 3x ds_read_b128 + 1x b64 per candidate.
//  * Phase A (all 16 waves): candidate screened with u * invL[sl] (3 muls,
//    invL = correctly-rounded 1/sl table). Exact 3-divide path only when
//    approx <= running_approx_min + MARGIN. Bound: |approx-exact| <= ~1e-11
//    << MARGIN, so every exact-min candidate (incl. all ties) IS exact-
//    evaluated, and non-triggered candidates are strictly worse: dp values,
//    argmins, first-occurrence ties bit-identical to the all-exact scan.
//  * Phase B (wave 0): serial 64-step chain over the precomputed sse
//    triangle; waves 1..15 concurrently precompute the NEXT block's triangle
//    (dp-independent) into the other sseT buffer.
// ---------------------------------------------------------------------------
__global__ __launch_bounds__(1024) void k_dp(const double* __restrict__ feat,
                                             int* __restrict__ bnd_g,
                                             int* __restrict__ nbnd_g,
                                             int* __restrict__ seg_s,
                                             int* __restrict__ seg_e,
                                             int* __restrict__ nseg_g) {
  __shared__ double cmb[NW + 1][8];            // 65,408 B
  __shared__ double sseT[2][DP_T][DP_T + 1];   // 66,560 B (buf0 = feat staging)
  __shared__ double pvL[DP_T][DP_NWAVE + 1];   // 8,704 B
  __shared__ int pixL[DP_T][DP_NWAVE + 1];     // 4,352 B
  __shared__ int prevL[NW + 1];                // 4,088 B
  __shared__ double invL[NW + 1];              // 8,176 B   (total ~157 KB)
  int b = blockIdx.x;
  int tid = threadIdx.x;
  const double* fb = feat + (size_t)b * NW * 3;

  // Stage feat into LDS (coalesced), build 1/sl table, init cmb[0].
  double* featS = &sseT[0][0][0];  // 4160 doubles >= NW*3 = 3063
  for (int i = tid; i < NW * 3; i += 1024) featS[i] = fb[i];
  for (int i = tid + 1; i <= NW; i += 1024) invL[i] = 1.0 / (double)i;
  if (tid == 0) {
    cmb[0][0] = 0.0; cmb[0][1] = 0.0; cmb[0][2] = 0.0;
    cmb[0][3] = 0.0; cmb[0][4] = 0.0; cmb[0][5] = 0.0;
    cmb[0][6] = -1.0;  // dp[0] = -penalty
  }
  __syncthreads();

  // 6 independent sequential prefix chains (3 ch x {sum, sumsq}); per-channel
  // accumulation order identical to np.cumsum -> bit-exact.
  if (tid < 6) {
    int c = tid % 3;
    bool sq = tid >= 3;
    int col = sq ? 3 + c : c;
    double acc = 0.0;
    for (int i = 0; i < NW; i++) {
      double f = featS[i * 3 + c];
      double v = sq ? f * f : f;
      acc = acc + v;
      cmb[i + 1][col] = acc;
    }
  }
  __syncthreads();

  int lane = tid & 63;   // end offset within block
  int w = tid >> 6;      // wave id 0..15

  // Prologue: triangle for block 0 into sseT[0] (featS fully consumed above).
  {
    int end = 1 + lane;
    double pe0 = cmb[end][0], pe1 = cmb[end][1], pe2 = cmb[end][2];
    double qe0 = cmb[end][3], qe1 = cmb[end][4], qe2 = cmb[end][5];
    for (int s = w; s < DP_T; s += DP_NWAVE) {
      int j = s;
      double sl = (double)(end - j);
      double s0 = pe0 - cmb[j][0], s1 = pe1 - cmb[j][1], s2 = pe2 - cmb[j][2];
      double u0 = s0 * s0, u1 = s1 * s1, u2 = s2 * s2;
      double t0 = (qe0 - cmb[j][3]) - u0 / sl;
      double t1 = (qe1 - cmb[j][4]) - u1 / sl;
      double t2 = (qe2 - cmb[j][5]) - u2 / sl;
      sseT[0][s][lane] = (t0 + t1) + t2;
    }
  }
  __syncthreads();

  double dpLast = -1.0;  // dp[e0] seen by wave 0 at phase-B entry (dp[0] = -1)

  for (int blk = 0; blk < DP_NBLK; blk++) {
    int cur = blk & 1, nxt = cur ^ 1;
    int e0 = blk * DP_T;
    int ecnt = NW - e0;
    if (ecnt > DP_T) ecnt = DP_T;
    int end = e0 + 1 + lane;
    if (end > NW) end = NW;  // clamp; writes are guarded by lane==s<ecnt
    double pe0 = cmb[end][0], pe1 = cmb[end][1], pe2 = cmb[end][2];
    double qe0 = cmb[end][3], qe1 = cmb[end][4], qe2 = cmb[end][5];
    double v = __builtin_inf();
    int ix = 0;
    double vminA = __builtin_inf();
    // Phase A: j in residue class w, ascending. Approx screen + exact trigger.
    for (int j = w; j < e0; j += DP_NWAVE) {
      double p0 = cmb[j][0], p1 = cmb[j][1], p2 = cmb[j][2];
      double q0 = cmb[j][3], q1 = cmb[j][4], q2 = cmb[j][5];
      double dpj = cmb[j][6];
      int sli = end - j;
      double inv = invL[sli];
      double s0 = pe0 - p0, s1 = pe1 - p1, s2 = pe2 - p2;
      double u0 = s0 * s0, u1 = s1 * s1, u2 = s2 * s2;
      double d0 = qe0 - q0, d1 = qe1 - q1, d2 = qe2 - q2;
      double ta0 = d0 - u0 * inv, ta1 = d1 - u1 * inv, ta2 = d2 - u2 * inv;
      double candA = (dpj + ((ta0 + ta1) + ta2)) + 1.0;
      if (candA <= vminA + DP_MARGIN) {
        double sl = (double)sli;
        double t0 = d0 - u0 / sl, t1 = d1 - u1 / sl, t2 = d2 - u2 / sl;
        double cand = (dpj + ((t0 + t1) + t2)) + 1.0;
        if (cand < v || (cand == v && j < ix)) { v = cand; ix = j; }
      }
      if (candA < vminA) vminA = candA;
    }
    pvL[lane][w] = v;
    pixL[lane][w] = ix;
    __syncthreads();
    if (w == 0) {
      // Merge wave partials: global first-occurrence argmin via ix tie-break.
      double vcur = pvL[lane][0];
      int ixcur = pixL[lane][0];
#pragma unroll
      for (int t = 1; t < DP_NWAVE; t++) {
        double ov = pvL[lane][t];
        int oi = pixL[lane][t];
        if (ov < vcur || (ov == vcur && oi < ixcur)) { vcur = ov; ixcur = oi; }
      }
      // Phase B: serial chain; sse precomputed, load double-buffered 1 ahead.
      double sse_next = sseT[cur][0][lane];
      for (int s = 0; s < ecnt; s++) {
        double sse_cur = sse_next;
        if (s + 1 < ecnt) sse_next = sseT[cur][s + 1][lane];
        double dpj = (s == 0) ? dpLast : __shfl(vcur, s - 1, 64);
        double cand = (dpj + sse_cur) + 1.0;
        if (lane >= s && cand < vcur) { vcur = cand; ixcur = e0 + s; }
        if (lane == s) {
          cmb[end][6] = vcur;
          prevL[end] = ixcur;
        }
      }
      dpLast = __shfl(vcur, ecnt - 1, 64);  // dp[e0 + ecnt] for next block
    } else if (blk + 1 < DP_NBLK) {
      // Waves 1..15: precompute next block's triangle (dp-independent).
      int e0n = e0 + DP_T;
      int ecn = NW - e0n;
      if (ecn > DP_T) ecn = DP_T;
      int endn = e0n + 1 + lane;
      if (endn > NW) endn = NW;
      double pn0 = cmb[endn][0], pn1 = cmb[endn][1], pn2 = cmb[endn][2];
      double qn0 = cmb[endn][3], qn1 = cmb[endn][4], qn2 = cmb[endn][5];
      for (int s = w - 1; s < ecn; s += DP_NWAVE - 1) {
        int j = e0n + s;
        double sl = (double)(endn - j);
        double s0 = pn0 - cmb[j][0], s1 = pn1 - cmb[j][1], s2 = pn2 - cmb[j][2];
        double u0 = s0 * s0, u1 = s1 * s1, u2 = s2 * s2;
        double t0 = (qn0 - cmb[j][3]) - u0 / sl;
        double t1 = (qn1 - cmb[j][4]) - u1 / sl;
        double t2 = (qn2 - cmb[j][5]) - u2 / sl;
        sseT[nxt][s][lane] = (t0 + t1) + t2;
      }
    }
    __syncthreads();
  }

  if (tid == 0) {
    int* chain = (int*)cmb;   // reuse LDS (cmb no longer needed)
    int cnt = 0, i = NW;
    while (i > 0) { i = prevL[i]; chain[cnt++] = i; }
    int* bbL = (int*)invL;    // reuse LDS (1026 ints fit in 8176 B)
    int nb = 0;
    bbL[nb++] = 0;
    for (int t = cnt - 2; t >= 0; t--) {  // interior breakpoints, ascending
      int w2 = chain[t];
      int tt = w2 * 8;
      if (tt <= bbL[nb - 1]) continue;
      if (tt - bbL[nb - 1] < 8) continue;
      if (LL - tt < 8) continue;
      bbL[nb++] = tt;
    }
    bbL[nb++] = LL;
    int* bb = bnd_g + (size_t)b * BNDCAP;
    for (int t = 0; t < nb; t++) bb[t] = bbL[t];
    nbnd_g[b] = nb;
    int nseg = nb - 1;
    nseg_g[b] = nseg;
    for (int si = 0; si < nseg; si++) {
      seg_s[(size_t)b * MAXSEG + si] = bbL[si];
      seg_e[(size_t)b * MAXSEG + si] = bbL[si + 1];
    }
  }
}

// ---------------------------------------------------------------------------
// Stage 4: all DFT bins of all segments, Goertzel + half-split.
// Segment [s,e), n = e-s (multiple of 8), owns flat bins [s/2, e/2),
// k = g - s/2 + 1. Thread (g, h in {0,1}) runs Goertzel over half h
// (m = n/2 elements): s_t = (a_t - s_{t+2}) + 2cos(th)*s_{t+1}, t desc.
// Partial S_h = Sum a_j e^{+i th j} = (s0 - cos*s1) + i sin*s1; the halves
// combine as X = S_0 + (-1)^k S_1 (since e^{i th m} = e^{i pi k} = (-1)^k),
// and |X|^2 equals the rfft power. 2 fp64 ops per (bin, element) vs 6 for
// the rotating-twiddle DFT; relative error ~1e-10 << float32 out quantum.
// fp contraction allowed: only power magnitudes feed robust decisions.
// ---------------------------------------------------------------------------
__global__ __launch_bounds__(512) void k_bins(const double* __restrict__ agg,
                                              const int* __restrict__ bnd_g,
                                              const int* __restrict__ nbnd_g,
                                              double* __restrict__ segp) {
#pragma clang fp contract(fast)
  __shared__ int bbS[BNDCAP];
  __shared__ double reS[512], imS[512];
  int b = blockIdx.y;
  int nb = nbnd_g[b];
  for (int i = threadIdx.x; i < nb; i += 512) bbS[i] = bnd_g[(size_t)b * BNDCAP + i];
  __syncthreads();
  int gl = threadIdx.x & 255;
  int h = threadIdx.x >> 8;       // half index 0/1
  int g = blockIdx.x * 256 + gl;  // flat bin 0..4095
  int pos = g * 2;
  int lo = 0, hi = nb - 1;
  while (hi - lo > 1) {
    int mid = (lo + hi) >> 1;
    if (bbS[mid] <= pos) lo = mid; else hi = mid;
  }
  int s = bbS[lo], e = bbS[lo + 1];
  int n = e - s;
  int k = g - s / 2 + 1;  // 1..n/2
  int m = n >> 1;         // per-half length; multiple of 4
  const double* ab = agg + (size_t)b * LL + s + h * m;
  double th = 6.283185307179586 * ((double)k / (double)n);
  double cth = cos(th), sth = sin(th);
  double c2 = 2.0 * cth;
  double s1 = 0.0, s2 = 0.0;
  for (int t = m - 4; t >= 0; t -= 4) {
    double a0 = ab[t + 0], a1 = ab[t + 1], a2 = ab[t + 2], a3 = ab[t + 3];
    double x0 = (a3 - s2) + c2 * s1;
    double x1 = (a2 - s1) + c2 * x0;
    double x2 = (a1 - x0) + c2 * x1;
    double x3 = (a0 - x1) + c2 * x2;
    s2 = x2; s1 = x3;
  }
  // s1 = s_0, s2 = s_1 ;  S_h = (s_0 - cos*s_1) + i sin*s_1
  double re = s1 - cth * s2;
  double im = sth * s2;
  reS[threadIdx.x] = re;
  imS[threadIdx.x] = im;
  __syncthreads();
  if (h == 0) {
    double re1 = reS[256 + gl], im1 = imS[256 + gl];
    double sgn = (k & 1) ? -1.0 : 1.0;
    double rr = re + sgn * re1;
    double ii = im + sgn * im1;
    segp[(size_t)b * NBINS + g] = rr * rr + ii * ii;
  }
}

// ---------------------------------------------------------------------------
// Stage 4c: per-segment stats from the flat power rows (staged in LDS).
// ---------------------------------------------------------------------------
__global__ __launch_bounds__(256) void k_segfin(
    const double* __restrict__ segp, const int* __restrict__ seg_s,
    const int* __restrict__ seg_e, const int* __restrict__ nseg_g,
    int* __restrict__ seg_pl, double* __restrict__ seg_domp,
    double* __restrict__ seg_bw) {
  __shared__ double ppS[NBINS];  // 32 KB
  int b = blockIdx.x;
  for (int i = threadIdx.x; i < NBINS; i += 256) ppS[i] = segp[(size_t)b * NBINS + i];
  __syncthreads();
  int ns = nseg_g[b];
  for (int si = threadIdx.x; si < ns; si += 256) {
    int s = seg_s[(size_t)b * MAXSEG + si];
    int e = seg_e[(size_t)b * MAXSEG + si];
    int n = e - s;
    int nb2 = n / 2;
    int base = s / 2;
    double domp, bwv;
    if (n < 2) {
      domp = 1.0; bwv = 0.0;
    } else if (nb2 <= 1) {
      domp = (double)n; bwv = 0.0;
    } else {
      const double* pp = ppS + base;
      double sum = np_pairwise([&](int i) { return pp[i]; }, 0, nb2);
      double tot = (sum > 1e-8) ? sum : 1e-8;
      int dom = 0;
      double bv = pp[0];
      for (int i = 1; i < nb2; i++)
        if (pp[i] > bv) { bv = pp[i]; dom = i; }
      dom += 1;
      double spf = np_pairwise([&](int i) { return pp[i] * (double)(i + 1); }, 0, nb2);
      double cent = spf / tot;
      double sv = np_pairwise(
          [&](int i) {
            double d = (double)(i + 1) - cent;
            double dd = d * d;
            return dd * pp[i];
          },
          0, nb2);
      double var = sv / tot;
      bwv = sqrt(var > 0.0 ? var : 0.0) / (double)n;
      domp = (double)n / (double)dom;
    }
    double raw = (1.0 * domp) / (1.0 + 1.0 * bwv);
    int pl = (int)rint(raw / 2.0) * 2;  // Python round = half-to-even
    if (pl < 8) pl = 8;
    if (pl > 64) pl = 64;
    seg_pl[(size_t)b * MAXSEG + si] = pl;
    seg_domp[(size_t)b * MAXSEG + si] = domp;
    seg_bw[(size_t)b * MAXSEG + si] = bwv;
  }
}

// ---------------------------------------------------------------------------
// Stage 5: token enumeration (one thread per batch) + n_tokens output.
// ---------------------------------------------------------------------------
__global__ void k_tokens(const int* __restrict__ seg_s, const int* __restrict__ seg_e,
                         const int* __restrict__ seg_pl, const int* __restrict__ nseg_g,
                         int* __restrict__ tok_a, int* __restrict__ tok_z,
                         int* __restrict__ tok_sg, int* __restrict__ ntok_g,
                         float* __restrict__ out_nt) {
  int b = blockIdx.x * blockDim.x + threadIdx.x;
  if (b >= BB) return;
  int ns = nseg_g[b];
  int cnt = 0;
  for (int si = 0; si < ns; si++) {
    int s = seg_s[(size_t)b * MAXSEG + si];
    int e = seg_e[(size_t)b * MAXSEG + si];
    int pl = seg_pl[(size_t)b * MAXSEG + si];
    for (int a = s; a < e; a += pl) {
      int z = a + pl;
      if (z > e) z = e;
      tok_a[(size_t)b * MAXTOK + cnt] = a;
      tok_z[(size_t)b * MAXTOK + cnt] = z;
      tok_sg[(size_t)b * MAXTOK + cnt] = si;
      cnt++;
    }
  }
  ntok_g[b] = cnt;
  out_nt[b] = (float)cnt;
}

// ---------------------------------------------------------------------------
// Stage 6: per-token metadata outputs. Padded tokens (t >= ntok) are
// zero-filled here (the big output memset is gone).
// ---------------------------------------------------------------------------
__global__ void k_tokfill(const int* __restrict__ tok_a, const int* __restrict__ tok_z,
                          const int* __restrict__ tok_sg, const int* __restrict__ ntok_g,
                          const int* __restrict__ seg_s, const int* __restrict__ seg_e,
                          const double* __restrict__ seg_domp,
                          const double* __restrict__ seg_bw, float* __restrict__ out,
                          int mx) {
  int b = blockIdx.x;
  int t = blockIdx.y * blockDim.x + threadIdx.x;
  if (t >= mx) return;
  size_t BM = (size_t)BB * (size_t)mx;
  float* mask = out + BM * 1024;
  float* start = mask + BM;
  float* endo = start + BM;
  float* cen = endo + BM;
  float* span = cen + BM;
  float* reg = span + BM;
  size_t o = (size_t)b * (size_t)mx + t;
  if (t >= ntok_g[b]) {
    mask[o] = 0.0f; start[o] = 0.0f; endo[o] = 0.0f;
    cen[o] = 0.0f; span[o] = 0.0f;
    reg[o * 3 + 0] = 0.0f; reg[o * 3 + 1] = 0.0f; reg[o * 3 + 2] = 0.0f;
    return;
  }
  int a = tok_a[(size_t)b * MAXTOK + t];
  int z = tok_z[(size_t)b * MAXTOK + t];
  int si = tok_sg[(size_t)b * MAXTOK + t];
  mask[o] = 1.0f;
  start[o] = (float)a;
  endo[o] = (float)z;
  cen[o] = (float)(((double)(a + z - 1) * 0.5) / 8191.0);
  span[o] = (float)((double)(z - a) / 8192.0);
  int s = seg_s[(size_t)b * MAXSEG + si];
  int e = seg_e[(size_t)b * MAXSEG + si];
  reg[o * 3 + 0] = (float)(seg_domp[(size_t)b * MAXSEG + si] / 8192.0);
  reg[o * 3 + 1] = (float)seg_bw[(size_t)b * MAXSEG + si];
  reg[o * 3 + 2] = (float)((double)(e - s) / 8192.0);
}

// ---------------------------------------------------------------------------
// Stage 7: patch gather. Padded tokens are zero-filled (memset removed).
// ---------------------------------------------------------------------------
__global__ __launch_bounds__(256) void k_patches(const float* __restrict__ x,
                                                 const int* __restrict__ tok_a,
                                                 const int* __restrict__ tok_z,
                                                 const int* __restrict__ ntok_g,
                                                 float* __restrict__ out, int mx) {
  int t = blockIdx.x, b = blockIdx.y;
  float* ob = out + (((size_t)b * (size_t)mx + t) * CC) * 16;
  if (t >= ntok_g[b]) {
    for (int e2 = threadIdx.x; e2 < CC * 16; e2 += 256) ob[e2] = 0.0f;
    return;
  }
  __shared__ int g0[16], g1[16];
  __shared__ float wS[16];
  if (threadIdx.x < 16) {
    int a = tok_a[(size_t)b * MAXTOK + t];
    int z = tok_z[(size_t)b * MAXTOK + t];
    int n = z - a;
    double src = ((double)threadIdx.x + 0.5) * ((double)n / 16.0) - 0.5;
    if (src < 0.0) src = 0.0;
    double hi = (double)n - 1.0;
    if (src > hi) src = hi;
    double fi = floor(src);
    int i0 = (int)fi;
    int i1 = i0 + 1;
    if (i1 > n - 1) i1 = n - 1;
    g0[threadIdx.x] = a + i0;
    g1[threadIdx.x] = a + i1;
    wS[threadIdx.x] = (float)(src - fi);
  }
  __syncthreads();
  const float* xb = x + (size_t)b * CC * LL;
  for (int e2 = threadIdx.x; e2 < CC * 16; e2 += 256) {
    int c = e2 >> 4, ai = e2 & 15;
    float wv = wS[ai];
    float v0 = xb[(size_t)c * LL + g0[ai]];
    float v1 = xb[(size_t)c * LL + g1[ai]];
    ob[e2] = v0 * (1.0f - wv) + v1 * wv;
  }
}

extern "C" void kernel_launch(void* const* d_in, const int* in_sizes, int n_in,
                              void* d_out, int out_size, void* d_ws, size_t ws_size,
                              hipStream_t stream) {
  (void)in_sizes; (void)n_in; (void)ws_size;
  const float* x = (const float*)d_in[0];
  float* out = (float*)d_out;
  // out_size = B*(1032*mx + 1)  -> recover mx
  long mx = ((long)out_size / BB - 1) / 1032;
  if (mx < 1) mx = 1;

  char* wp = (char*)d_ws;
  size_t off = 0;
  auto carve = [&](size_t bytes) -> void* {
    void* p = wp + off;
    off += (bytes + 255) & ~(size_t)255;
    return p;
  };
  double* agg = (double*)carve((size_t)BB * LL * 8);
  double* feat = (double*)carve((size_t)BB * NW * 3 * 8);
  double* segp = (double*)carve((size_t)BB * NBINS * 8);
  double* seg_domp = (double*)carve((size_t)BB * MAXSEG * 8);
  double* seg_bw = (double*)carve((size_t)BB * MAXSEG * 8);
  int* bnd = (int*)carve((size_t)BB * BNDCAP * 4);
  int* nbnd = (int*)carve((size_t)BB * 4);
  int* seg_s = (int*)carve((size_t)BB * MAXSEG * 4);
  int* seg_e = (int*)carve((size_t)BB * MAXSEG * 4);
  int* seg_pl = (int*)carve((size_t)BB * MAXSEG * 4);
  int* nseg = (int*)carve((size_t)BB * 4);
  int* tok_a = (int*)carve((size_t)BB * MAXTOK * 4);
  int* tok_z = (int*)carve((size_t)BB * MAXTOK * 4);
  int* tok_sg = (int*)carve((size_t)BB * MAXTOK * 4);
  int* ntok = (int*)carve((size_t)BB * 4);

  k_agg<<<(BB * LL + 255) / 256, 256, 0, stream>>>(x, agg);
  k_winfeat<<<(BB * NW + 255) / 256, 256, 0, stream>>>(agg, feat);
  k_dp<<<BB, 1024, 0, stream>>>(feat, bnd, nbnd, seg_s, seg_e, nseg);
  dim3 gb(NBINS / 256, BB);
  k_bins<<<gb, 512, 0, stream>>>(agg, bnd, nbnd, segp);
  k_segfin<<<BB, 256, 0, stream>>>(segp, seg_s, seg_e, nseg, seg_pl, seg_domp,
                                   seg_bw);
  k_tokens<<<1, 64, 0, stream>>>(seg_s, seg_e, seg_pl, nseg, tok_a, tok_z,
                                 tok_sg, ntok, out + (size_t)BB * (size_t)mx * 1032);
  dim3 gf(BB, (unsigned)((mx + 255) / 256));
  k_tokfill<<<gf, 256, 0, stream>>>(tok_a, tok_z, tok_sg, ntok, seg_s, seg_e,
                                    seg_domp, seg_bw, out, (int)mx);
  dim3 gp((unsigned)mx, BB);
  k_patches<<<gp, 256, 0, stream>>>(x, tok_a, tok_z, ntok, out, (int)mx);
}

// Round 5
// 1003.092 us; speedup vs baseline: 1.6631x; 1.2457x over previous
//
#include <hip/hip_runtime.h>
#include <math.h>

#pragma clang fp contract(off)

#define BB 32
#define CC 64
#define LL 8192
#define NW 1021      // number of spectral windows: (8192-32)/8 + 1
#define MAXSEG 1024
#define MAXTOK 1024
#define BNDCAP 1026
#define NBINS (LL / 2)   // 4096 flat bins per batch (segments partition [0,L))

// DP blocking parameters
#define DP_T 64          // ends per block
#define DP_NBLK 16       // ceil(NW / DP_T)
#define DP_NWAVE 16      // waves per workgroup (1024 threads)
#define DP_MARGIN 1e-6   // approx->exact trigger margin; approx err <= ~1e-12

// ---------------------------------------------------------------------------
// numpy pairwise_sum replica (loops.c.src): n<8 sequential, n<=128 blocked with
// 8 accumulators, else recursive halving with n2 -= n2 % 8.
// ---------------------------------------------------------------------------
template <typename F>
__device__ double np_pairwise(const F& f, int off, int n) {
  if (n < 8) {
    double res = 0.0;
    for (int i = 0; i < n; i++) res = res + f(off + i);
    return res;
  }
  if (n <= 128) {
    double r0 = f(off + 0), r1 = f(off + 1), r2 = f(off + 2), r3 = f(off + 3);
    double r4 = f(off + 4), r5 = f(off + 5), r6 = f(off + 6), r7 = f(off + 7);
    int i = 8;
    int lim = n - (n % 8);
    for (; i < lim; i += 8) {
      r0 = r0 + f(off + i + 0); r1 = r1 + f(off + i + 1);
      r2 = r2 + f(off + i + 2); r3 = r3 + f(off + i + 3);
      r4 = r4 + f(off + i + 4); r5 = r5 + f(off + i + 5);
      r6 = r6 + f(off + i + 6); r7 = r7 + f(off + i + 7);
    }
    double res = ((r0 + r1) + (r2 + r3)) + ((r4 + r5) + (r6 + r7));
    for (; i < n; i++) res = res + f(off + i);
    return res;
  }
  int n2 = n / 2;
  n2 -= n2 % 8;
  return np_pairwise(f, off, n2) + np_pairwise(f, off + n2, n - n2);
}

// ---------------------------------------------------------------------------
// Wave-parallel exact replica of numpy pairwise_sum.
// Leaf (n in [8,128]): numpy's 8 accumulators map to lanes k = lane&7; each
// r_k accumulates f(off+8i+k) in numpy's order; combine via shfl_xor 1,2,4
// gives ((r0+r1)+(r2+r3))+((r4+r5)+(r6+r7)) (fp add commutative -> bit-exact);
// tail added serially. All 64 lanes end with the identical result.
// KIND: 0 = pp[i], 1 = pp[i]*(i+1), 2 = ((i+1)-cent)^2*pp[i].
// ---------------------------------------------------------------------------
template <int KIND>
__device__ __noinline__ double wp_leaf(const double* __restrict__ pp, double cent,
                                       int off, int n, int lane) {
  int k = lane & 7;
  auto f = [&](int i) -> double {
    double pv = pp[i];
    if constexpr (KIND == 0) {
      return pv;
    } else if constexpr (KIND == 1) {
      return pv * (double)(i + 1);
    } else {
      double d = (double)(i + 1) - cent;
      double dd = d * d;
      return dd * pv;
    }
  };
  double r = f(off + k);
  int lim = n - (n % 8);
  for (int i = 8; i < lim; i += 8) r = r + f(off + i + k);
  double a = r + __shfl_xor(r, 1, 64);
  double b2 = a + __shfl_xor(a, 2, 64);
  double res = b2 + __shfl_xor(b2, 4, 64);
  for (int i = lim; i < n; i++) res = res + f(off + i);
  return res;
}

template <int DEPTH, int KIND>
__device__ double wp_tree(const double* __restrict__ pp, double cent, int off,
                          int n, int lane) {
  if (n <= 128) return wp_leaf<KIND>(pp, cent, off, n, lane);
  if constexpr (DEPTH > 0) {
    int n2 = n / 2;
    n2 -= n2 % 8;
    double l = wp_tree<DEPTH - 1, KIND>(pp, cent, off, n2, lane);
    double r = wp_tree<DEPTH - 1, KIND>(pp, cent, off + n2, n - n2, lane);
    return l + r;
  } else {
    // exact serial fallback (unreachable for n <= 8192 with DEPTH=7)
    if constexpr (KIND == 0)
      return np_pairwise([&](int i) { return pp[i]; }, off, n);
    else if constexpr (KIND == 1)
      return np_pairwise([&](int i) { return pp[i] * (double)(i + 1); }, off, n);
    else
      return np_pairwise(
          [&](int i) {
            double d = (double)(i + 1) - cent;
            double dd = d * d;
            return dd * pp[i];
          },
          off, n);
  }
}

// ---------------------------------------------------------------------------
// Stage 1: agg[b][l] = channel mean, numpy sequential f32 order.
// ---------------------------------------------------------------------------
__global__ void k_agg(const float* __restrict__ x, double* __restrict__ agg) {
  int idx = blockIdx.x * blockDim.x + threadIdx.x;
  if (idx >= BB * LL) return;
  int b = idx / LL, l = idx - b * LL;
  const float* xb = x + (size_t)b * CC * LL + l;
  float s = 0.0f;
  for (int c = 0; c < CC; c++) s = s + xb[(size_t)c * LL];
  agg[idx] = (double)(s / 64.0f);
}

// ---------------------------------------------------------------------------
// Stage 2: per-window spectral features (32-pt DFT, bins 1..16).
// ---------------------------------------------------------------------------
__global__ void k_winfeat(const double* __restrict__ agg, double* __restrict__ feat) {
  __shared__ double tc[32], tsn[32];
  if (threadIdx.x < 32) {
    double th = 6.283185307179586 * ((double)threadIdx.x / 32.0);
    tc[threadIdx.x] = cos(th);
    tsn[threadIdx.x] = sin(th);
  }
  __syncthreads();
  int idx = blockIdx.x * blockDim.x + threadIdx.x;
  if (idx >= BB * NW) return;
  int b = idx / NW, w = idx - b * NW;
  const double* a = agg + (size_t)b * LL + (size_t)w * 8;
  double av[32];
#pragma unroll
  for (int t = 0; t < 32; t++) av[t] = a[t];
  double p[16];
  for (int k = 1; k <= 16; k++) {
    double re = 0.0, im = 0.0;
    int m = 0;
    for (int t = 0; t < 32; t++) {
      re = re + av[t] * tc[m];
      im = im + av[t] * tsn[m];
      m = (m + k) & 31;
    }
    p[k - 1] = re * re + im * im;
  }
  double r[8];
  for (int i = 0; i < 8; i++) r[i] = p[i] + p[i + 8];
  double sum = ((r[0] + r[1]) + (r[2] + r[3])) + ((r[4] + r[5]) + (r[6] + r[7]));
  double tot = (sum > 1e-8) ? sum : 1e-8;
  double pf[16];
  for (int i = 0; i < 16; i++) pf[i] = p[i] * (double)(i + 1);
  for (int i = 0; i < 8; i++) r[i] = pf[i] + pf[i + 8];
  double spf = ((r[0] + r[1]) + (r[2] + r[3])) + ((r[4] + r[5]) + (r[6] + r[7]));
  int dom = 0;
  double bv = p[0];
  for (int i = 1; i < 16; i++)
    if (p[i] > bv) { bv = p[i]; dom = i; }
  dom += 1;
  double cent = spf / tot;
  double q[16];
  for (int i = 0; i < 16; i++) {
    double d = (double)(i + 1) - cent;
    double dd = d * d;
    q[i] = dd * p[i];
  }
  for (int i = 0; i < 8; i++) r[i] = q[i] + q[i + 8];
  double sv = ((r[0] + r[1]) + (r[2] + r[3])) + ((r[4] + r[5]) + (r[6] + r[7]));
  double var = sv / tot;
  double bw = sqrt(var > 0.0 ? var : 0.0) / 32.0;
  double mean = sum / 16.0;
  double* f = feat + ((size_t)b * NW + (size_t)w) * 3;
  f[0] = (double)dom / 32.0;
  f[1] = bw;
  f[2] = log1p(mean);
}

// ---------------------------------------------------------------------------
// Stage 3: PELT DP, blocked, three-phase exact evaluation.
//  cmb[j] = {p0,p1,p2,qs,dp,q0,q1,q2} (qs = (q0+q1)+q2 precomputed).
//  Scan 1 (all waves): pure-approx candA = (dp[j] + (dsum - usum*inv)) + 1
//    (no divides, no index) -> per-class min -> LDS -> global approx min mA
//    per end (merged across all 16 classes).
//  Scan 2: recompute candA; exact 3-divide path only when candA <= mA+MARGIN
//    -> ~1-2 triggers per end TOTAL (not per class), so the wave pays the
//    divide body ~6x per block instead of every iteration (r2's screen used
//    a per-class running min: any-lane-trigger fired ~every iteration).
//  Bound: |candA - cand_exact| <= ~2e-12 (values ~1e3, ~10 ops) << MARGIN, so
//  every exact-min/tie candidate is exact-evaluated with the reference op
//  order; non-triggered candidates are strictly worse -> dp values, argmins,
//  first-occurrence ties bit-identical.
//  Phase B (wave 0): serial chain over precomputed sse triangle; waves 1..15
//  concurrently precompute the NEXT block's triangle.
// ---------------------------------------------------------------------------
__global__ __launch_bounds__(1024) void k_dp(const double* __restrict__ feat,
                                             int* __restrict__ bnd_g,
                                             int* __restrict__ nbnd_g,
                                             int* __restrict__ seg_s,
                                             int* __restrict__ seg_e,
                                             int* __restrict__ nseg_g) {
  __shared__ double cmb[NW + 1][8];            // 65,408 B
  __shared__ double sseT[2][DP_T][DP_T + 1];   // 66,560 B (buf0 = feat staging)
  __shared__ double pvL[DP_T][DP_NWAVE + 1];   // 8,704 B
  __shared__ int pixL[DP_T][DP_NWAVE + 1];     // 4,352 B
  __shared__ int prevL[NW + 1];                // 4,088 B
  __shared__ double invL[NW + 1];              // 8,176 B   (total ~157 KB)
  int b = blockIdx.x;
  int tid = threadIdx.x;
  const double* fb = feat + (size_t)b * NW * 3;

  // Stage feat into LDS (coalesced), build 1/sl table, init cmb[0].
  double* featS = &sseT[0][0][0];  // 4160 doubles >= NW*3 = 3063
  for (int i = tid; i < NW * 3; i += 1024) featS[i] = fb[i];
  for (int i = tid + 1; i <= NW; i += 1024) invL[i] = 1.0 / (double)i;
  if (tid == 0) {
    cmb[0][0] = 0.0; cmb[0][1] = 0.0; cmb[0][2] = 0.0;
    cmb[0][3] = 0.0;   // qs
    cmb[0][4] = -1.0;  // dp[0] = -penalty
    cmb[0][5] = 0.0; cmb[0][6] = 0.0; cmb[0][7] = 0.0;
  }
  __syncthreads();

  // 6 independent sequential prefix chains (3 ch x {sum, sumsq}); per-channel
  // accumulation order identical to np.cumsum -> bit-exact.
  if (tid < 6) {
    int c = tid % 3;
    bool sq = tid >= 3;
    int col = sq ? 5 + c : c;
    double acc = 0.0;
    for (int i = 0; i < NW; i++) {
      double f = featS[i * 3 + c];
      double v = sq ? f * f : f;
      acc = acc + v;
      cmb[i + 1][col] = acc;
    }
  }
  __syncthreads();

  int lane = tid & 63;   // end offset within block
  int w = tid >> 6;      // wave id 0..15

  // qs fill (reads cols 5..7, writes col 3 - disjoint from triangle's reads).
  for (int i = tid + 1; i <= NW; i += 1024)
    cmb[i][3] = (cmb[i][5] + cmb[i][6]) + cmb[i][7];
  // Prologue: triangle for block 0 into sseT[0] (featS fully consumed above).
  {
    int end = 1 + lane;
    double pe0 = cmb[end][0], pe1 = cmb[end][1], pe2 = cmb[end][2];
    double qe0 = cmb[end][5], qe1 = cmb[end][6], qe2 = cmb[end][7];
    for (int s = w; s < DP_T; s += DP_NWAVE) {
      int j = s;
      double sl = (double)(end - j);
      double s0 = pe0 - cmb[j][0], s1 = pe1 - cmb[j][1], s2 = pe2 - cmb[j][2];
      double u0 = s0 * s0, u1 = s1 * s1, u2 = s2 * s2;
      double t0 = (qe0 - cmb[j][5]) - u0 / sl;
      double t1 = (qe1 - cmb[j][6]) - u1 / sl;
      double t2 = (qe2 - cmb[j][7]) - u2 / sl;
      sseT[0][s][lane] = (t0 + t1) + t2;
    }
  }
  __syncthreads();

  double dpLast = -1.0;  // dp[e0] seen by wave 0 at phase-B entry (dp[0] = -1)

  for (int blk = 0; blk < DP_NBLK; blk++) {
    int cur = blk & 1, nxt = cur ^ 1;
    int e0 = blk * DP_T;
    int ecnt = NW - e0;
    if (ecnt > DP_T) ecnt = DP_T;
    int end = e0 + 1 + lane;
    if (end > NW) end = NW;  // clamp; writes are guarded by lane==s<ecnt
    double pe0 = cmb[end][0], pe1 = cmb[end][1], pe2 = cmb[end][2];
    double qeS = cmb[end][3];
    // Scan 1: pure approx, per-class min (value only, no branchy body).
    double vminA = __builtin_inf();
    for (int j = w; j < e0; j += DP_NWAVE) {
      double p0 = cmb[j][0], p1 = cmb[j][1], p2 = cmb[j][2];
      double qs = cmb[j][3], dpj = cmb[j][4];
      double inv = invL[end - j];
      double s0 = pe0 - p0, s1 = pe1 - p1, s2 = pe2 - p2;
      double u0 = s0 * s0, u1 = s1 * s1, u2 = s2 * s2;
      double us = (u0 + u1) + u2;
      double ds = qeS - qs;
      double candA = (dpj + (ds - us * inv)) + 1.0;
      if (candA < vminA) vminA = candA;
    }
    pvL[lane][w] = vminA;
    __syncthreads();
    // Merge approx min across classes (redundant in every wave).
    double mA = pvL[lane][0];
#pragma unroll
    for (int t = 1; t < DP_NWAVE; t++) {
      double ov = pvL[lane][t];
      if (ov < mA) mA = ov;
    }
    double thr = mA + DP_MARGIN;
    __syncthreads();  // protect pvL reads from scan-2 overwrites
    // Scan 2: exact path only within margin of the GLOBAL approx min.
    double v = __builtin_inf();
    int ix = 0;
    for (int j = w; j < e0; j += DP_NWAVE) {
      double p0 = cmb[j][0], p1 = cmb[j][1], p2 = cmb[j][2];
      double qs = cmb[j][3], dpj = cmb[j][4];
      double inv = invL[end - j];
      double s0 = pe0 - p0, s1 = pe1 - p1, s2 = pe2 - p2;
      double u0 = s0 * s0, u1 = s1 * s1, u2 = s2 * s2;
      double us = (u0 + u1) + u2;
      double ds = qeS - qs;
      double candA = (dpj + (ds - us * inv)) + 1.0;
      if (candA <= thr) {
        double qe0 = cmb[end][5], qe1 = cmb[end][6], qe2 = cmb[end][7];
        double q0 = cmb[j][5], q1 = cmb[j][6], q2 = cmb[j][7];
        double sl = (double)(end - j);
        double t0 = (qe0 - q0) - u0 / sl;
        double t1 = (qe1 - q1) - u1 / sl;
        double t2 = (qe2 - q2) - u2 / sl;
        double cand = (dpj + ((t0 + t1) + t2)) + 1.0;
        if (cand < v || (cand == v && j < ix)) { v = cand; ix = j; }
      }
    }
    pvL[lane][w] = v;
    pixL[lane][w] = ix;
    __syncthreads();
    if (w == 0) {
      // Merge wave partials: global first-occurrence argmin via ix tie-break.
      double vcur = pvL[lane][0];
      int ixcur = pixL[lane][0];
#pragma unroll
      for (int t = 1; t < DP_NWAVE; t++) {
        double ov = pvL[lane][t];
        int oi = pixL[lane][t];
        if (ov < vcur || (ov == vcur && oi < ixcur)) { vcur = ov; ixcur = oi; }
      }
      // Phase B: serial chain; sse precomputed, load double-buffered 1 ahead.
      double sse_next = sseT[cur][0][lane];
      for (int s = 0; s < ecnt; s++) {
        double sse_cur = sse_next;
        if (s + 1 < ecnt) sse_next = sseT[cur][s + 1][lane];
        double dpj = (s == 0) ? dpLast : __shfl(vcur, s - 1, 64);
        double cand = (dpj + sse_cur) + 1.0;
        if (lane >= s && cand < vcur) { vcur = cand; ixcur = e0 + s; }
        if (lane == s) {
          cmb[end][4] = vcur;
          prevL[end] = ixcur;
        }
      }
      dpLast = __shfl(vcur, ecnt - 1, 64);  // dp[e0 + ecnt] for next block
    } else if (blk + 1 < DP_NBLK) {
      // Waves 1..15: precompute next block's triangle (dp-independent).
      int e0n = e0 + DP_T;
      int ecn = NW - e0n;
      if (ecn > DP_T) ecn = DP_T;
      int endn = e0n + 1 + lane;
      if (endn > NW) endn = NW;
      double pn0 = cmb[endn][0], pn1 = cmb[endn][1], pn2 = cmb[endn][2];
      double qn0 = cmb[endn][5], qn1 = cmb[endn][6], qn2 = cmb[endn][7];
      for (int s = w - 1; s < ecn; s += DP_NWAVE - 1) {
        int j = e0n + s;
        double sl = (double)(endn - j);
        double s0 = pn0 - cmb[j][0], s1 = pn1 - cmb[j][1], s2 = pn2 - cmb[j][2];
        double u0 = s0 * s0, u1 = s1 * s1, u2 = s2 * s2;
        double t0 = (qn0 - cmb[j][5]) - u0 / sl;
        double t1 = (qn1 - cmb[j][6]) - u1 / sl;
        double t2 = (qn2 - cmb[j][7]) - u2 / sl;
        sseT[nxt][s][lane] = (t0 + t1) + t2;
      }
    }
    __syncthreads();
  }

  if (tid == 0) {
    int* chain = (int*)cmb;   // reuse LDS (cmb no longer needed)
    int cnt = 0, i = NW;
    while (i > 0) { i = prevL[i]; chain[cnt++] = i; }
    int* bbL = (int*)invL;    // reuse LDS (1026 ints fit in 8176 B)
    int nb = 0;
    bbL[nb++] = 0;
    for (int t = cnt - 2; t >= 0; t--) {  // interior breakpoints, ascending
      int w2 = chain[t];
      int tt = w2 * 8;
      if (tt <= bbL[nb - 1]) continue;
      if (tt - bbL[nb - 1] < 8) continue;
      if (LL - tt < 8) continue;
      bbL[nb++] = tt;
    }
    bbL[nb++] = LL;
    int* bb = bnd_g + (size_t)b * BNDCAP;
    for (int t = 0; t < nb; t++) bb[t] = bbL[t];
    nbnd_g[b] = nb;
    int nseg = nb - 1;
    nseg_g[b] = nseg;
    for (int si = 0; si < nseg; si++) {
      seg_s[(size_t)b * MAXSEG + si] = bbL[si];
      seg_e[(size_t)b * MAXSEG + si] = bbL[si + 1];
    }
  }
}

// ---------------------------------------------------------------------------
// Stage 4: all DFT bins of all segments, Goertzel + half-split.
// ---------------------------------------------------------------------------
__global__ __launch_bounds__(512) void k_bins(const double* __restrict__ agg,
                                              const int* __restrict__ bnd_g,
                                              const int* __restrict__ nbnd_g,
                                              double* __restrict__ segp) {
#pragma clang fp contract(fast)
  __shared__ int bbS[BNDCAP];
  __shared__ double reS[512], imS[512];
  int b = blockIdx.y;
  int nb = nbnd_g[b];
  for (int i = threadIdx.x; i < nb; i += 512) bbS[i] = bnd_g[(size_t)b * BNDCAP + i];
  __syncthreads();
  int gl = threadIdx.x & 255;
  int h = threadIdx.x >> 8;       // half index 0/1
  int g = blockIdx.x * 256 + gl;  // flat bin 0..4095
  int pos = g * 2;
  int lo = 0, hi = nb - 1;
  while (hi - lo > 1) {
    int mid = (lo + hi) >> 1;
    if (bbS[mid] <= pos) lo = mid; else hi = mid;
  }
  int s = bbS[lo], e = bbS[lo + 1];
  int n = e - s;
  int k = g - s / 2 + 1;  // 1..n/2
  int m = n >> 1;         // per-half length; multiple of 4
  const double* ab = agg + (size_t)b * LL + s + h * m;
  double th = 6.283185307179586 * ((double)k / (double)n);
  double cth = cos(th), sth = sin(th);
  double c2 = 2.0 * cth;
  double s1 = 0.0, s2 = 0.0;
  for (int t = m - 4; t >= 0; t -= 4) {
    double a0 = ab[t + 0], a1 = ab[t + 1], a2 = ab[t + 2], a3 = ab[t + 3];
    double x0 = (a3 - s2) + c2 * s1;
    double x1 = (a2 - s1) + c2 * x0;
    double x2 = (a1 - x0) + c2 * x1;
    double x3 = (a0 - x1) + c2 * x2;
    s2 = x2; s1 = x3;
  }
  double re = s1 - cth * s2;
  double im = sth * s2;
  reS[threadIdx.x] = re;
  imS[threadIdx.x] = im;
  __syncthreads();
  if (h == 0) {
    double re1 = reS[256 + gl], im1 = imS[256 + gl];
    double sgn = (k & 1) ? -1.0 : 1.0;
    double rr = re + sgn * re1;
    double ii = im + sgn * im1;
    segp[(size_t)b * NBINS + g] = rr * rr + ii * ii;
  }
}

// ---------------------------------------------------------------------------
// Stage 4c: per-segment stats, one WAVE per segment (was one thread). The
// pairwise sums use the exact numpy tree (wp_tree); argmax is chunked per
// lane with (greater value, smaller index) reduction = first occurrence.
// ---------------------------------------------------------------------------
__global__ __launch_bounds__(256) void k_segfin(
    const double* __restrict__ segp, const int* __restrict__ seg_s,
    const int* __restrict__ seg_e, const int* __restrict__ nseg_g,
    int* __restrict__ seg_pl, double* __restrict__ seg_domp,
    double* __restrict__ seg_bw) {
  __shared__ double ppS[NBINS];  // 32 KB
  int b = blockIdx.x;
  for (int i = threadIdx.x; i < NBINS; i += 256) ppS[i] = segp[(size_t)b * NBINS + i];
  __syncthreads();
  int ns = nseg_g[b];
  int lane = threadIdx.x & 63;
  int wid = threadIdx.x >> 6;
  for (int si = wid; si < ns; si += 4) {
    int s = seg_s[(size_t)b * MAXSEG + si];
    int e = seg_e[(size_t)b * MAXSEG + si];
    int n = e - s;
    int nb2 = n / 2;
    int base = s / 2;
    double domp, bwv;
    if (n < 2) {
      domp = 1.0; bwv = 0.0;
    } else if (nb2 <= 1) {
      domp = (double)n; bwv = 0.0;
    } else {
      const double* pp = ppS + base;
      double sum, spf, sv;
      if (nb2 < 8) {
        sum = 0.0;
        for (int i = 0; i < nb2; i++) sum = sum + pp[i];
      } else {
        sum = wp_tree<7, 0>(pp, 0.0, 0, nb2, lane);
      }
      double tot = (sum > 1e-8) ? sum : 1e-8;
      // argmax, first occurrence: contiguous chunks, strict > ascending,
      // cross-lane prefer (greater value, smaller index).
      int ch = (nb2 + 63) >> 6;
      double bv = -1.0;
      int bi = 0x7fffffff;
      int st = lane * ch;
      int en2 = st + ch;
      if (en2 > nb2) en2 = nb2;
      if (st < nb2) {
        bv = pp[st]; bi = st;
        for (int i = st + 1; i < en2; i++) {
          double pv = pp[i];
          if (pv > bv) { bv = pv; bi = i; }
        }
      }
      for (int o = 32; o; o >>= 1) {
        double ov = __shfl_xor(bv, o, 64);
        int oi = __shfl_xor(bi, o, 64);
        if (ov > bv || (ov == bv && oi < bi)) { bv = ov; bi = oi; }
      }
      int dom = bi + 1;
      if (nb2 < 8) {
        spf = 0.0;
        for (int i = 0; i < nb2; i++) spf = spf + pp[i] * (double)(i + 1);
      } else {
        spf = wp_tree<7, 1>(pp, 0.0, 0, nb2, lane);
      }
      double cent = spf / tot;
      if (nb2 < 8) {
        sv = 0.0;
        for (int i = 0; i < nb2; i++) {
          double d = (double)(i + 1) - cent;
          double dd = d * d;
          sv = sv + dd * pp[i];
        }
      } else {
        sv = wp_tree<7, 2>(pp, cent, 0, nb2, lane);
      }
      double var = sv / tot;
      bwv = sqrt(var > 0.0 ? var : 0.0) / (double)n;
      domp = (double)n / (double)dom;
    }
    double raw = (1.0 * domp) / (1.0 + 1.0 * bwv);
    int pl = (int)rint(raw / 2.0) * 2;  // Python round = half-to-even
    if (pl < 8) pl = 8;
    if (pl > 64) pl = 64;
    if (lane == 0) {
      seg_pl[(size_t)b * MAXSEG + si] = pl;
      seg_domp[(size_t)b * MAXSEG + si] = domp;
      seg_bw[(size_t)b * MAXSEG + si] = bwv;
    }
  }
}

// ---------------------------------------------------------------------------
// Stage 5: token enumeration (one thread per batch) + n_tokens output.
// ---------------------------------------------------------------------------
__global__ void k_tokens(const int* __restrict__ seg_s, const int* __restrict__ seg_e,
                         const int* __restrict__ seg_pl, const int* __restrict__ nseg_g,
                         int* __restrict__ tok_a, int* __restrict__ tok_z,
                         int* __restrict__ tok_sg, int* __restrict__ ntok_g,
                         float* __restrict__ out_nt) {
  int b = blockIdx.x * blockDim.x + threadIdx.x;
  if (b >= BB) return;
  int ns = nseg_g[b];
  int cnt = 0;
  for (int si = 0; si < ns; si++) {
    int s = seg_s[(size_t)b * MAXSEG + si];
    int e = seg_e[(size_t)b * MAXSEG + si];
    int pl = seg_pl[(size_t)b * MAXSEG + si];
    for (int a = s; a < e; a += pl) {
      int z = a + pl;
      if (z > e) z = e;
      tok_a[(size_t)b * MAXTOK + cnt] = a;
      tok_z[(size_t)b * MAXTOK + cnt] = z;
      tok_sg[(size_t)b * MAXTOK + cnt] = si;
      cnt++;
    }
  }
  ntok_g[b] = cnt;
  out_nt[b] = (float)cnt;
}

// ---------------------------------------------------------------------------
// Stage 6: per-token metadata outputs. Padded tokens (t >= ntok) are
// zero-filled here (the big output memset is gone).
// ---------------------------------------------------------------------------
__global__ void k_tokfill(const int* __restrict__ tok_a, const int* __restrict__ tok_z,
                          const int* __restrict__ tok_sg, const int* __restrict__ ntok_g,
                          const int* __restrict__ seg_s, const int* __restrict__ seg_e,
                          const double* __restrict__ seg_domp,
                          const double* __restrict__ seg_bw, float* __restrict__ out,
                          int mx) {
  int b = blockIdx.x;
  int t = blockIdx.y * blockDim.x + threadIdx.x;
  if (t >= mx) return;
  size_t BM = (size_t)BB * (size_t)mx;
  float* mask = out + BM * 1024;
  float* start = mask + BM;
  float* endo = start + BM;
  float* cen = endo + BM;
  float* span = cen + BM;
  float* reg = span + BM;
  size_t o = (size_t)b * (size_t)mx + t;
  if (t >= ntok_g[b]) {
    mask[o] = 0.0f; start[o] = 0.0f; endo[o] = 0.0f;
    cen[o] = 0.0f; span[o] = 0.0f;
    reg[o * 3 + 0] = 0.0f; reg[o * 3 + 1] = 0.0f; reg[o * 3 + 2] = 0.0f;
    return;
  }
  int a = tok_a[(size_t)b * MAXTOK + t];
  int z = tok_z[(size_t)b * MAXTOK + t];
  int si = tok_sg[(size_t)b * MAXTOK + t];
  mask[o] = 1.0f;
  start[o] = (float)a;
  endo[o] = (float)z;
  cen[o] = (float)(((double)(a + z - 1) * 0.5) / 8191.0);
  span[o] = (float)((double)(z - a) / 8192.0);
  int s = seg_s[(size_t)b * MAXSEG + si];
  int e = seg_e[(size_t)b * MAXSEG + si];
  reg[o * 3 + 0] = (float)(seg_domp[(size_t)b * MAXSEG + si] / 8192.0);
  reg[o * 3 + 1] = (float)seg_bw[(size_t)b * MAXSEG + si];
  reg[o * 3 + 2] = (float)((double)(e - s) / 8192.0);
}

// ---------------------------------------------------------------------------
// Stage 7: patch gather. Padded tokens are zero-filled (memset removed).
// ---------------------------------------------------------------------------
__global__ __launch_bounds__(256) void k_patches(const float* __restrict__ x,
                                                 const int* __restrict__ tok_a,
                                                 const int* __restrict__ tok_z,
                                                 const int* __restrict__ ntok_g,
                                                 float* __restrict__ out, int mx) {
  int t = blockIdx.x, b = blockIdx.y;
  float* ob = out + (((size_t)b * (size_t)mx + t) * CC) * 16;
  if (t >= ntok_g[b]) {
    for (int e2 = threadIdx.x; e2 < CC * 16; e2 += 256) ob[e2] = 0.0f;
    return;
  }
  __shared__ int g0[16], g1[16];
  __shared__ float wS[16];
  if (threadIdx.x < 16) {
    int a = tok_a[(size_t)b * MAXTOK + t];
    int z = tok_z[(size_t)b * MAXTOK + t];
    int n = z - a;
    double src = ((double)threadIdx.x + 0.5) * ((double)n / 16.0) - 0.5;
    if (src < 0.0) src = 0.0;
    double hi = (double)n - 1.0;
    if (src > hi) src = hi;
    double fi = floor(src);
    int i0 = (int)fi;
    int i1 = i0 + 1;
    if (i1 > n - 1) i1 = n - 1;
    g0[threadIdx.x] = a + i0;
    g1[threadIdx.x] = a + i1;
    wS[threadIdx.x] = (float)(src - fi);
  }
  __syncthreads();
  const float* xb = x + (size_t)b * CC * LL;
  for (int e2 = threadIdx.x; e2 < CC * 16; e2 += 256) {
    int c = e2 >> 4, ai = e2 & 15;
    float wv = wS[ai];
    float v0 = xb[(size_t)c * LL + g0[ai]];
    float v1 = xb[(size_t)c * LL + g1[ai]];
    ob[e2] = v0 * (1.0f - wv) + v1 * wv;
  }
}

extern "C" void kernel_launch(void* const* d_in, const int* in_sizes, int n_in,
                              void* d_out, int out_size, void* d_ws, size_t ws_size,
                              hipStream_t stream) {
  (void)in_sizes; (void)n_in; (void)ws_size;
  const float* x = (const float*)d_in[0];
  float* out = (float*)d_out;
  // out_size = B*(1032*mx + 1)  -> recover mx
  long mx = ((long)out_size / BB - 1) / 1032;
  if (mx < 1) mx = 1;

  char* wp = (char*)d_ws;
  size_t off = 0;
  auto carve = [&](size_t bytes) -> void* {
    void* p = wp + off;
    off += (bytes + 255) & ~(size_t)255;
    return p;
  };
  double* agg = (double*)carve((size_t)BB * LL * 8);
  double* feat = (double*)carve((size_t)BB * NW * 3 * 8);
  double* segp = (double*)carve((size_t)BB * NBINS * 8);
  double* seg_domp = (double*)carve((size_t)BB * MAXSEG * 8);
  double* seg_bw = (double*)carve((size_t)BB * MAXSEG * 8);
  int* bnd = (int*)carve((size_t)BB * BNDCAP * 4);
  int* nbnd = (int*)carve((size_t)BB * 4);
  int* seg_s = (int*)carve((size_t)BB * MAXSEG * 4);
  int* seg_e = (int*)carve((size_t)BB * MAXSEG * 4);
  int* seg_pl = (int*)carve((size_t)BB * MAXSEG * 4);
  int* nseg = (int*)carve((size_t)BB * 4);
  int* tok_a = (int*)carve((size_t)BB * MAXTOK * 4);
  int* tok_z = (int*)carve((size_t)BB * MAXTOK * 4);
  int* tok_sg = (int*)carve((size_t)BB * MAXTOK * 4);
  int* ntok = (int*)carve((size_t)BB * 4);

  k_agg<<<(BB * LL + 255) / 256, 256, 0, stream>>>(x, agg);
  k_winfeat<<<(BB * NW + 255) / 256, 256, 0, stream>>>(agg, feat);
  k_dp<<<BB, 1024, 0, stream>>>(feat, bnd, nbnd, seg_s, seg_e, nseg);
  dim3 gb(NBINS / 256, BB);
  k_bins<<<gb, 512, 0, stream>>>(agg, bnd, nbnd, segp);
  k_segfin<<<BB, 256, 0, stream>>>(segp, seg_s, seg_e, nseg, seg_pl, seg_domp,
                                   seg_bw);
  k_tokens<<<1, 64, 0, stream>>>(seg_s, seg_e, seg_pl, nseg, tok_a, tok_z,
                                 tok_sg, ntok, out + (size_t)BB * (size_t)mx * 1032);
  dim3 gf(BB, (unsigned)((mx + 255) / 256));
  k_tokfill<<<gf, 256, 0, stream>>>(tok_a, tok_z, tok_sg, ntok, seg_s, seg_e,
                                    seg_domp, seg_bw, out, (int)mx);
  dim3 gp((unsigned)mx, BB);
  k_patches<<<gp, 256, 0, stream>>>(x, tok_a, tok_z, ntok, out, (int)mx);
}

// Round 6
// 867.955 us; speedup vs baseline: 1.9221x; 1.1557x over previous
//
#include <hip/hip_runtime.h>
#include <math.h>

#pragma clang fp contract(off)

#define BB 32
#define CC 64
#define LL 8192
#define NW 1021      // number of spectral windows: (8192-32)/8 + 1
#define MAXSEG 1024
#define MAXTOK 1024
#define BNDCAP 1026
#define NBINS (LL / 2)   // 4096 flat bins per batch (segments partition [0,L))

// DP blocking parameters
#define DP_T 64          // ends per block
#define DP_NBLK 16       // ceil(NW / DP_T)
#define DP_MARGIN 1e-6   // screen margin; approx-vs-exact error <= ~1e-11

// ---------------------------------------------------------------------------
// numpy pairwise_sum replica (loops.c.src): n<8 sequential, n<=128 blocked with
// 8 accumulators, else recursive halving with n2 -= n2 % 8.
// ---------------------------------------------------------------------------
template <typename F>
__device__ double np_pairwise(const F& f, int off, int n) {
  if (n < 8) {
    double res = 0.0;
    for (int i = 0; i < n; i++) res = res + f(off + i);
    return res;
  }
  if (n <= 128) {
    double r0 = f(off + 0), r1 = f(off + 1), r2 = f(off + 2), r3 = f(off + 3);
    double r4 = f(off + 4), r5 = f(off + 5), r6 = f(off + 6), r7 = f(off + 7);
    int i = 8;
    int lim = n - (n % 8);
    for (; i < lim; i += 8) {
      r0 = r0 + f(off + i + 0); r1 = r1 + f(off + i + 1);
      r2 = r2 + f(off + i + 2); r3 = r3 + f(off + i + 3);
      r4 = r4 + f(off + i + 4); r5 = r5 + f(off + i + 5);
      r6 = r6 + f(off + i + 6); r7 = r7 + f(off + i + 7);
    }
    double res = ((r0 + r1) + (r2 + r3)) + ((r4 + r5) + (r6 + r7));
    for (; i < n; i++) res = res + f(off + i);
    return res;
  }
  int n2 = n / 2;
  n2 -= n2 % 8;
  return np_pairwise(f, off, n2) + np_pairwise(f, off + n2, n - n2);
}

// ---------------------------------------------------------------------------
// Wave-parallel exact replica of numpy pairwise_sum (see r4 notes).
// ---------------------------------------------------------------------------
template <int KIND>
__device__ __noinline__ double wp_leaf(const double* __restrict__ pp, double cent,
                                       int off, int n, int lane) {
  int k = lane & 7;
  auto f = [&](int i) -> double {
    double pv = pp[i];
    if constexpr (KIND == 0) {
      return pv;
    } else if constexpr (KIND == 1) {
      return pv * (double)(i + 1);
    } else {
      double d = (double)(i + 1) - cent;
      double dd = d * d;
      return dd * pv;
    }
  };
  double r = f(off + k);
  int lim = n - (n % 8);
  for (int i = 8; i < lim; i += 8) r = r + f(off + i + k);
  double a = r + __shfl_xor(r, 1, 64);
  double b2 = a + __shfl_xor(a, 2, 64);
  double res = b2 + __shfl_xor(b2, 4, 64);
  for (int i = lim; i < n; i++) res = res + f(off + i);
  return res;
}

template <int DEPTH, int KIND>
__device__ double wp_tree(const double* __restrict__ pp, double cent, int off,
                          int n, int lane) {
  if (n <= 128) return wp_leaf<KIND>(pp, cent, off, n, lane);
  if constexpr (DEPTH > 0) {
    int n2 = n / 2;
    n2 -= n2 % 8;
    double l = wp_tree<DEPTH - 1, KIND>(pp, cent, off, n2, lane);
    double r = wp_tree<DEPTH - 1, KIND>(pp, cent, off + n2, n - n2, lane);
    return l + r;
  } else {
    if constexpr (KIND == 0)
      return np_pairwise([&](int i) { return pp[i]; }, off, n);
    else if constexpr (KIND == 1)
      return np_pairwise([&](int i) { return pp[i] * (double)(i + 1); }, off, n);
    else
      return np_pairwise(
          [&](int i) {
            double d = (double)(i + 1) - cent;
            double dd = d * d;
            return dd * pp[i];
          },
          off, n);
  }
}

// ---------------------------------------------------------------------------
// Stage 1: agg[b][l] = channel mean, numpy sequential f32 order.
// ---------------------------------------------------------------------------
__global__ void k_agg(const float* __restrict__ x, double* __restrict__ agg) {
  int idx = blockIdx.x * blockDim.x + threadIdx.x;
  if (idx >= BB * LL) return;
  int b = idx / LL, l = idx - b * LL;
  const float* xb = x + (size_t)b * CC * LL + l;
  float s = 0.0f;
  for (int c = 0; c < CC; c++) s = s + xb[(size_t)c * LL];
  agg[idx] = (double)(s / 64.0f);
}

// ---------------------------------------------------------------------------
// Stage 2: per-window spectral features (32-pt DFT, bins 1..16).
// ---------------------------------------------------------------------------
__global__ void k_winfeat(const double* __restrict__ agg, double* __restrict__ feat) {
  __shared__ double tc[32], tsn[32];
  if (threadIdx.x < 32) {
    double th = 6.283185307179586 * ((double)threadIdx.x / 32.0);
    tc[threadIdx.x] = cos(th);
    tsn[threadIdx.x] = sin(th);
  }
  __syncthreads();
  int idx = blockIdx.x * blockDim.x + threadIdx.x;
  if (idx >= BB * NW) return;
  int b = idx / NW, w = idx - b * NW;
  const double* a = agg + (size_t)b * LL + (size_t)w * 8;
  double av[32];
#pragma unroll
  for (int t = 0; t < 32; t++) av[t] = a[t];
  double p[16];
  for (int k = 1; k <= 16; k++) {
    double re = 0.0, im = 0.0;
    int m = 0;
    for (int t = 0; t < 32; t++) {
      re = re + av[t] * tc[m];
      im = im + av[t] * tsn[m];
      m = (m + k) & 31;
    }
    p[k - 1] = re * re + im * im;
  }
  double r[8];
  for (int i = 0; i < 8; i++) r[i] = p[i] + p[i + 8];
  double sum = ((r[0] + r[1]) + (r[2] + r[3])) + ((r[4] + r[5]) + (r[6] + r[7]));
  double tot = (sum > 1e-8) ? sum : 1e-8;
  double pf[16];
  for (int i = 0; i < 16; i++) pf[i] = p[i] * (double)(i + 1);
  for (int i = 0; i < 8; i++) r[i] = pf[i] + pf[i + 8];
  double spf = ((r[0] + r[1]) + (r[2] + r[3])) + ((r[4] + r[5]) + (r[6] + r[7]));
  int dom = 0;
  double bv = p[0];
  for (int i = 1; i < 16; i++)
    if (p[i] > bv) { bv = p[i]; dom = i; }
  dom += 1;
  double cent = spf / tot;
  double q[16];
  for (int i = 0; i < 16; i++) {
    double d = (double)(i + 1) - cent;
    double dd = d * d;
    q[i] = dd * p[i];
  }
  for (int i = 0; i < 8; i++) r[i] = q[i] + q[i + 8];
  double sv = ((r[0] + r[1]) + (r[2] + r[3])) + ((r[4] + r[5]) + (r[6] + r[7]));
  double var = sv / tot;
  double bw = sqrt(var > 0.0 ? var : 0.0) / 32.0;
  double mean = sum / 16.0;
  double* f = feat + ((size_t)b * NW + (size_t)w) * 3;
  f[0] = (double)dom / 32.0;
  f[1] = bw;
  f[2] = log1p(mean);
}

// ---------------------------------------------------------------------------
// Stage 3: PELT DP — overlapped schedule.
//  cmb[j] = {p0,p1,p2, w, dp, q0,q1,q2}, w = dp[j]+1-qs[j] (screen-only fold;
//  written by wave 0 during Phase B using a register qs).
//  Per block k, SEG A (concurrent, disjoint LDS ranges):
//   wave 0:  merge pvL (23 classes) for ends E_k -> Phase B serial chain for
//            block k (writes dp, prev, w for rows e0+1..e0+64).
//   waves 1..15: triangle for block k+1 into sseT[nxt] + FULL scan for block
//            k+1's ends over j < e0_k (15 classes, j = (w-1) mod 15; reads
//            only rows j < e0 and rows > e0+64 -> no overlap with wave 0).
//            Screen: top-2 approx (m1, ix1, m2); if m2-m1 > MARGIN the approx
//            argmin is provably the unique exact argmin (eps ~1e-11): one
//            exact eval. Else exact rescan with threshold m1+MARGIN.
//            dp values / argmins / first-occurrence ties bit-identical.
//  SEG B: waves commit (v,ix) to pvL rows 0..14; waves 0..7 short-scan the
//   64 just-finalized j in [e0_k, e0_k+64) (8 j each) -> rows 15..22.
//  2 barriers per block; the O(NW^2) scan rides under Phase B.
// ---------------------------------------------------------------------------
__global__ __launch_bounds__(1024) void k_dp(const double* __restrict__ feat,
                                             int* __restrict__ bnd_g,
                                             int* __restrict__ nbnd_g,
                                             int* __restrict__ seg_s,
                                             int* __restrict__ seg_e,
                                             int* __restrict__ nseg_g) {
  __shared__ double cmb[NW + 1][8];        // 65,408 B
  __shared__ double sseT[2][DP_T][DP_T];   // 65,536 B (buf0 doubles as staging)
  __shared__ double pvL[24][DP_T];         // 12,288 B  [class][lane]
  __shared__ int pixL[24][DP_T];           //  6,144 B
  __shared__ int prevL[NW + 1];            //  4,088 B
  __shared__ double invL[NW + 1];          //  8,176 B   total 161,640 B
  int b = blockIdx.x;
  int tid = threadIdx.x;
  const double* fb = feat + (size_t)b * NW * 3;

  double* featS = &sseT[0][0][0];  // 4096 doubles >= NW*3 = 3063
  for (int i = tid; i < NW * 3; i += 1024) featS[i] = fb[i];
  for (int i = tid + 1; i <= NW; i += 1024) invL[i] = 1.0 / (double)i;
  for (int i = tid; i < 24 * DP_T; i += 1024) {
    (&pvL[0][0])[i] = __builtin_inf();
    (&pixL[0][0])[i] = 0;
  }
  if (tid == 0) {
    cmb[0][0] = 0.0; cmb[0][1] = 0.0; cmb[0][2] = 0.0;
    cmb[0][3] = 0.0;   // w0 = dp0 + 1 - qs0 = 0
    cmb[0][4] = -1.0;  // dp[0] = -penalty
    cmb[0][5] = 0.0; cmb[0][6] = 0.0; cmb[0][7] = 0.0;
  }
  __syncthreads();

  // 6 sequential prefix chains (3 ch x {sum,sumsq}); np.cumsum order exact.
  if (tid < 6) {
    int c = tid % 3;
    bool sq = tid >= 3;
    int col = sq ? 5 + c : c;
    double acc = 0.0;
    for (int i = 0; i < NW; i++) {
      double f = featS[i * 3 + c];
      double v = sq ? f * f : f;
      acc = acc + v;
      cmb[i + 1][col] = acc;
    }
  }
  __syncthreads();

  int lane = tid & 63;
  int w = tid >> 6;

  // Prologue: triangle for block 0 (featS fully consumed above).
  {
    int end = 1 + lane;
    double pe0 = cmb[end][0], pe1 = cmb[end][1], pe2 = cmb[end][2];
    double qe0 = cmb[end][5], qe1 = cmb[end][6], qe2 = cmb[end][7];
    for (int s = w; s < DP_T; s += 16) {
      double sl = (double)(end - s);
      double s0 = pe0 - cmb[s][0], s1 = pe1 - cmb[s][1], s2 = pe2 - cmb[s][2];
      double u0 = s0 * s0, u1 = s1 * s1, u2 = s2 * s2;
      double t0 = (qe0 - cmb[s][5]) - u0 / sl;
      double t1 = (qe1 - cmb[s][6]) - u1 / sl;
      double t2 = (qe2 - cmb[s][7]) - u2 / sl;
      sseT[0][s][lane] = (t0 + t1) + t2;
    }
  }
  __syncthreads();

  double dpLast = -1.0;

  for (int blk = 0; blk < DP_NBLK; blk++) {
    int cur = blk & 1, nxt = cur ^ 1;
    int e0 = blk * DP_T;
    int ecnt = NW - e0;
    if (ecnt > DP_T) ecnt = DP_T;
    bool hasNext = (blk + 1 < DP_NBLK);
    double vBig = __builtin_inf();
    int ixBig = 0;

    // ---- SEG A ----
    if (w == 0) {
      int end = e0 + 1 + lane;
      if (end > NW) end = NW;
      double vcur = pvL[0][lane];
      int ixcur = pixL[0][lane];
#pragma unroll
      for (int t = 1; t < 23; t++) {
        double ov = pvL[t][lane];
        int oi = pixL[t][lane];
        if (ov < vcur || (ov == vcur && oi < ixcur)) { vcur = ov; ixcur = oi; }
      }
      double qsE = (cmb[end][5] + cmb[end][6]) + cmb[end][7];
      // Phase B serial chain over the precomputed triangle.
      double sse_next = sseT[cur][0][lane];
      for (int s = 0; s < ecnt; s++) {
        double sse_cur = sse_next;
        if (s + 1 < ecnt) sse_next = sseT[cur][s + 1][lane];
        double dpj = (s == 0) ? dpLast : __shfl(vcur, s - 1, 64);
        double cand = (dpj + sse_cur) + 1.0;
        if (lane >= s && cand < vcur) { vcur = cand; ixcur = e0 + s; }
        if (lane == s) {
          cmb[end][4] = vcur;
          prevL[end] = ixcur;
          cmb[end][3] = (vcur + 1.0) - qsE;  // screen fold w
        }
      }
      dpLast = __shfl(vcur, ecnt - 1, 64);
    } else if (hasNext) {
      int e0n = e0 + DP_T;
      int ecn = NW - e0n;
      if (ecn > DP_T) ecn = DP_T;
      int endn = e0n + 1 + lane;
      if (endn > NW) endn = NW;
      double pn0 = cmb[endn][0], pn1 = cmb[endn][1], pn2 = cmb[endn][2];
      double qn0 = cmb[endn][5], qn1 = cmb[endn][6], qn2 = cmb[endn][7];
      // Triangle for block blk+1.
      for (int s = w - 1; s < ecn; s += 15) {
        int j = e0n + s;
        double sl = (double)(endn - j);
        double s0 = pn0 - cmb[j][0], s1 = pn1 - cmb[j][1], s2 = pn2 - cmb[j][2];
        double u0 = s0 * s0, u1 = s1 * s1, u2 = s2 * s2;
        double t0 = (qn0 - cmb[j][5]) - u0 / sl;
        double t1 = (qn1 - cmb[j][6]) - u1 / sl;
        double t2 = (qn2 - cmb[j][7]) - u2 / sl;
        sseT[nxt][s][lane] = (t0 + t1) + t2;
      }
      // Big scan for E_{blk+1} over j < e0, class (w-1) mod 15, top-2 screen.
      double qeS = (qn0 + qn1) + qn2;
      double m1 = __builtin_inf(), m2 = __builtin_inf();
      int ix1 = -1;
      for (int j = w - 1; j < e0; j += 15) {
        double p0 = cmb[j][0], p1 = cmb[j][1], p2 = cmb[j][2], wj = cmb[j][3];
        double inv = invL[endn - j];
        double s0 = pn0 - p0, s1 = pn1 - p1, s2 = pn2 - p2;
        double us = fma(s2, s2, fma(s1, s1, s0 * s0));
        double candA = fma(-us, inv, wj + qeS);
        if (candA < m1) { m2 = m1; m1 = candA; ix1 = j; }
        else if (candA < m2) { m2 = candA; }
      }
      if (ix1 >= 0) {
        if (m2 - m1 > DP_MARGIN) {
          int j = ix1;
          double p0 = cmb[j][0], p1 = cmb[j][1], p2 = cmb[j][2];
          double q0 = cmb[j][5], q1 = cmb[j][6], q2 = cmb[j][7];
          double dpj = cmb[j][4];
          double sl = (double)(endn - j);
          double s0 = pn0 - p0, s1 = pn1 - p1, s2 = pn2 - p2;
          double u0 = s0 * s0, u1 = s1 * s1, u2 = s2 * s2;
          double t0 = (qn0 - q0) - u0 / sl;
          double t1 = (qn1 - q1) - u1 / sl;
          double t2 = (qn2 - q2) - u2 / sl;
          vBig = (dpj + ((t0 + t1) + t2)) + 1.0;
          ixBig = j;
        } else {
          double thr = m1 + DP_MARGIN;
          for (int j = w - 1; j < e0; j += 15) {
            double p0 = cmb[j][0], p1 = cmb[j][1], p2 = cmb[j][2], wj = cmb[j][3];
            double inv = invL[endn - j];
            double s0 = pn0 - p0, s1 = pn1 - p1, s2 = pn2 - p2;
            double us = fma(s2, s2, fma(s1, s1, s0 * s0));
            double candA = fma(-us, inv, wj + qeS);
            if (candA <= thr) {
              double q0 = cmb[j][5], q1 = cmb[j][6], q2 = cmb[j][7];
              double dpj = cmb[j][4];
              double sl = (double)(endn - j);
              double u0 = s0 * s0, u1 = s1 * s1, u2 = s2 * s2;
              double t0 = (qn0 - q0) - u0 / sl;
              double t1 = (qn1 - q1) - u1 / sl;
              double t2 = (qn2 - q2) - u2 / sl;
              double cand = (dpj + ((t0 + t1) + t2)) + 1.0;
              if (cand < vBig || (cand == vBig && j < ixBig)) { vBig = cand; ixBig = j; }
            }
          }
        }
      }
    }
    __syncthreads();
    // ---- SEG B ----
    if (hasNext) {
      if (w >= 1) {
        pvL[w - 1][lane] = vBig;
        pixL[w - 1][lane] = ixBig;
      }
      if (w < 8) {
        int e0n = e0 + DP_T;
        int endn = e0n + 1 + lane;
        if (endn > NW) endn = NW;
        double pn0 = cmb[endn][0], pn1 = cmb[endn][1], pn2 = cmb[endn][2];
        double qn0 = cmb[endn][5], qn1 = cmb[endn][6], qn2 = cmb[endn][7];
        double qeS = (qn0 + qn1) + qn2;
        double m1 = __builtin_inf(), m2 = __builtin_inf();
        int ix1 = 0;
        int j0 = e0 + w * 8;
        for (int i = 0; i < 8; i++) {
          int j = j0 + i;
          double p0 = cmb[j][0], p1 = cmb[j][1], p2 = cmb[j][2], wj = cmb[j][3];
          double inv = invL[endn - j];
          double s0 = pn0 - p0, s1 = pn1 - p1, s2 = pn2 - p2;
          double us = fma(s2, s2, fma(s1, s1, s0 * s0));
          double candA = fma(-us, inv, wj + qeS);
          if (candA < m1) { m2 = m1; m1 = candA; ix1 = j; }
          else if (candA < m2) { m2 = candA; }
        }
        double v = __builtin_inf();
        int ix = 0;
        if (m2 - m1 > DP_MARGIN) {
          int j = ix1;
          double p0 = cmb[j][0], p1 = cmb[j][1], p2 = cmb[j][2];
          double q0 = cmb[j][5], q1 = cmb[j][6], q2 = cmb[j][7];
          double dpj = cmb[j][4];
          double sl = (double)(endn - j);
          double s0 = pn0 - p0, s1 = pn1 - p1, s2 = pn2 - p2;
          double u0 = s0 * s0, u1 = s1 * s1, u2 = s2 * s2;
          double t0 = (qn0 - q0) - u0 / sl;
          double t1 = (qn1 - q1) - u1 / sl;
          double t2 = (qn2 - q2) - u2 / sl;
          v = (dpj + ((t0 + t1) + t2)) + 1.0;
          ix = j;
        } else {
          double thr = m1 + DP_MARGIN;
          for (int i = 0; i < 8; i++) {
            int j = j0 + i;
            double p0 = cmb[j][0], p1 = cmb[j][1], p2 = cmb[j][2], wj = cmb[j][3];
            double inv = invL[endn - j];
            double s0 = pn0 - p0, s1 = pn1 - p1, s2 = pn2 - p2;
            double us = fma(s2, s2, fma(s1, s1, s0 * s0));
            double candA = fma(-us, inv, wj + qeS);
            if (candA <= thr) {
              double q0 = cmb[j][5], q1 = cmb[j][6], q2 = cmb[j][7];
              double dpj = cmb[j][4];
              double sl = (double)(endn - j);
              double u0 = s0 * s0, u1 = s1 * s1, u2 = s2 * s2;
              double t0 = (qn0 - q0) - u0 / sl;
              double t1 = (qn1 - q1) - u1 / sl;
              double t2 = (qn2 - q2) - u2 / sl;
              double cand = (dpj + ((t0 + t1) + t2)) + 1.0;
              if (cand < v || (cand == v && j < ix)) { v = cand; ix = j; }
            }
          }
        }
        pvL[15 + w][lane] = v;
        pixL[15 + w][lane] = ix;
      }
    }
    __syncthreads();
  }

  if (tid == 0) {
    int* chain = (int*)cmb;   // reuse LDS
    int cnt = 0, i = NW;
    while (i > 0) { i = prevL[i]; chain[cnt++] = i; }
    int* bbL = (int*)invL;    // reuse LDS (1026 ints fit in 8176 B)
    int nb = 0;
    bbL[nb++] = 0;
    for (int t = cnt - 2; t >= 0; t--) {  // interior breakpoints, ascending
      int w2 = chain[t];
      int tt = w2 * 8;
      if (tt <= bbL[nb - 1]) continue;
      if (tt - bbL[nb - 1] < 8) continue;
      if (LL - tt < 8) continue;
      bbL[nb++] = tt;
    }
    bbL[nb++] = LL;
    int* bb = bnd_g + (size_t)b * BNDCAP;
    for (int t = 0; t < nb; t++) bb[t] = bbL[t];
    nbnd_g[b] = nb;
    int nseg = nb - 1;
    nseg_g[b] = nseg;
    for (int si = 0; si < nseg; si++) {
      seg_s[(size_t)b * MAXSEG + si] = bbL[si];
      seg_e[(size_t)b * MAXSEG + si] = bbL[si + 1];
    }
  }
}

// ---------------------------------------------------------------------------
// Stage 4: all DFT bins of all segments, Goertzel + half-split.
// ---------------------------------------------------------------------------
__global__ __launch_bounds__(512) void k_bins(const double* __restrict__ agg,
                                              const int* __restrict__ bnd_g,
                                              const int* __restrict__ nbnd_g,
                                              double* __restrict__ segp) {
#pragma clang fp contract(fast)
  __shared__ int bbS[BNDCAP];
  __shared__ double reS[512], imS[512];
  int b = blockIdx.y;
  int nb = nbnd_g[b];
  for (int i = threadIdx.x; i < nb; i += 512) bbS[i] = bnd_g[(size_t)b * BNDCAP + i];
  __syncthreads();
  int gl = threadIdx.x & 255;
  int h = threadIdx.x >> 8;       // half index 0/1
  int g = blockIdx.x * 256 + gl;  // flat bin 0..4095
  int pos = g * 2;
  int lo = 0, hi = nb - 1;
  while (hi - lo > 1) {
    int mid = (lo + hi) >> 1;
    if (bbS[mid] <= pos) lo = mid; else hi = mid;
  }
  int s = bbS[lo], e = bbS[lo + 1];
  int n = e - s;
  int k = g - s / 2 + 1;  // 1..n/2
  int m = n >> 1;         // per-half length; multiple of 4
  const double* ab = agg + (size_t)b * LL + s + h * m;
  double th = 6.283185307179586 * ((double)k / (double)n);
  double cth = cos(th), sth = sin(th);
  double c2 = 2.0 * cth;
  double s1 = 0.0, s2 = 0.0;
  for (int t = m - 4; t >= 0; t -= 4) {
    double a0 = ab[t + 0], a1 = ab[t + 1], a2 = ab[t + 2], a3 = ab[t + 3];
    double x0 = (a3 - s2) + c2 * s1;
    double x1 = (a2 - s1) + c2 * x0;
    double x2 = (a1 - x0) + c2 * x1;
    double x3 = (a0 - x1) + c2 * x2;
    s2 = x2; s1 = x3;
  }
  double re = s1 - cth * s2;
  double im = sth * s2;
  reS[threadIdx.x] = re;
  imS[threadIdx.x] = im;
  __syncthreads();
  if (h == 0) {
    double re1 = reS[256 + gl], im1 = imS[256 + gl];
    double sgn = (k & 1) ? -1.0 : 1.0;
    double rr = re + sgn * re1;
    double ii = im + sgn * im1;
    segp[(size_t)b * NBINS + g] = rr * rr + ii * ii;
  }
}

// ---------------------------------------------------------------------------
// Stage 4c: per-segment stats, one wave per segment (exact numpy replicas).
// ---------------------------------------------------------------------------
__global__ __launch_bounds__(256) void k_segfin(
    const double* __restrict__ segp, const int* __restrict__ seg_s,
    const int* __restrict__ seg_e, const int* __restrict__ nseg_g,
    int* __restrict__ seg_pl, double* __restrict__ seg_domp,
    double* __restrict__ seg_bw) {
  __shared__ double ppS[NBINS];  // 32 KB
  int b = blockIdx.x;
  for (int i = threadIdx.x; i < NBINS; i += 256) ppS[i] = segp[(size_t)b * NBINS + i];
  __syncthreads();
  int ns = nseg_g[b];
  int lane = threadIdx.x & 63;
  int wid = threadIdx.x >> 6;
  for (int si = wid; si < ns; si += 4) {
    int s = seg_s[(size_t)b * MAXSEG + si];
    int e = seg_e[(size_t)b * MAXSEG + si];
    int n = e - s;
    int nb2 = n / 2;
    int base = s / 2;
    double domp, bwv;
    if (n < 2) {
      domp = 1.0; bwv = 0.0;
    } else if (nb2 <= 1) {
      domp = (double)n; bwv = 0.0;
    } else {
      const double* pp = ppS + base;
      double sum, spf, sv;
      if (nb2 < 8) {
        sum = 0.0;
        for (int i = 0; i < nb2; i++) sum = sum + pp[i];
      } else {
        sum = wp_tree<7, 0>(pp, 0.0, 0, nb2, lane);
      }
      double tot = (sum > 1e-8) ? sum : 1e-8;
      int ch = (nb2 + 63) >> 6;
      double bv = -1.0;
      int bi = 0x7fffffff;
      int st = lane * ch;
      int en2 = st + ch;
      if (en2 > nb2) en2 = nb2;
      if (st < nb2) {
        bv = pp[st]; bi = st;
        for (int i = st + 1; i < en2; i++) {
          double pv = pp[i];
          if (pv > bv) { bv = pv; bi = i; }
        }
      }
      for (int o = 32; o; o >>= 1) {
        double ov = __shfl_xor(bv, o, 64);
        int oi = __shfl_xor(bi, o, 64);
        if (ov > bv || (ov == bv && oi < bi)) { bv = ov; bi = oi; }
      }
      int dom = bi + 1;
      if (nb2 < 8) {
        spf = 0.0;
        for (int i = 0; i < nb2; i++) spf = spf + pp[i] * (double)(i + 1);
      } else {
        spf = wp_tree<7, 1>(pp, 0.0, 0, nb2, lane);
      }
      double cent = spf / tot;
      if (nb2 < 8) {
        sv = 0.0;
        for (int i = 0; i < nb2; i++) {
          double d = (double)(i + 1) - cent;
          double dd = d * d;
          sv = sv + dd * pp[i];
        }
      } else {
        sv = wp_tree<7, 2>(pp, cent, 0, nb2, lane);
      }
      double var = sv / tot;
      bwv = sqrt(var > 0.0 ? var : 0.0) / (double)n;
      domp = (double)n / (double)dom;
    }
    double raw = (1.0 * domp) / (1.0 + 1.0 * bwv);
    int pl = (int)rint(raw / 2.0) * 2;  // Python round = half-to-even
    if (pl < 8) pl = 8;
    if (pl > 64) pl = 64;
    if (lane == 0) {
      seg_pl[(size_t)b * MAXSEG + si] = pl;
      seg_domp[(size_t)b * MAXSEG + si] = domp;
      seg_bw[(size_t)b * MAXSEG + si] = bwv;
    }
  }
}

// ---------------------------------------------------------------------------
// Stage 5: token enumeration (one thread per batch) + n_tokens output.
// ---------------------------------------------------------------------------
__global__ void k_tokens(const int* __restrict__ seg_s, const int* __restrict__ seg_e,
                         const int* __restrict__ seg_pl, const int* __restrict__ nseg_g,
                         int* __restrict__ tok_a, int* __restrict__ tok_z,
                         int* __restrict__ tok_sg, int* __restrict__ ntok_g,
                         float* __restrict__ out_nt) {
  int b = blockIdx.x * blockDim.x + threadIdx.x;
  if (b >= BB) return;
  int ns = nseg_g[b];
  int cnt = 0;
  for (int si = 0; si < ns; si++) {
    int s = seg_s[(size_t)b * MAXSEG + si];
    int e = seg_e[(size_t)b * MAXSEG + si];
    int pl = seg_pl[(size_t)b * MAXSEG + si];
    for (int a = s; a < e; a += pl) {
      int z = a + pl;
      if (z > e) z = e;
      tok_a[(size_t)b * MAXTOK + cnt] = a;
      tok_z[(size_t)b * MAXTOK + cnt] = z;
      tok_sg[(size_t)b * MAXTOK + cnt] = si;
      cnt++;
    }
  }
  ntok_g[b] = cnt;
  out_nt[b] = (float)cnt;
}

// ---------------------------------------------------------------------------
// Stage 6: per-token metadata outputs (zero-fills padding; no big memset).
// ---------------------------------------------------------------------------
__global__ void k_tokfill(const int* __restrict__ tok_a, const int* __restrict__ tok_z,
                          const int* __restrict__ tok_sg, const int* __restrict__ ntok_g,
                          const int* __restrict__ seg_s, const int* __restrict__ seg_e,
                          const double* __restrict__ seg_domp,
                          const double* __restrict__ seg_bw, float* __restrict__ out,
                          int mx) {
  int b = blockIdx.x;
  int t = blockIdx.y * blockDim.x + threadIdx.x;
  if (t >= mx) return;
  size_t BM = (size_t)BB * (size_t)mx;
  float* mask = out + BM * 1024;
  float* start = mask + BM;
  float* endo = start + BM;
  float* cen = endo + BM;
  float* span = cen + BM;
  float* reg = span + BM;
  size_t o = (size_t)b * (size_t)mx + t;
  if (t >= ntok_g[b]) {
    mask[o] = 0.0f; start[o] = 0.0f; endo[o] = 0.0f;
    cen[o] = 0.0f; span[o] = 0.0f;
    reg[o * 3 + 0] = 0.0f; reg[o * 3 + 1] = 0.0f; reg[o * 3 + 2] = 0.0f;
    return;
  }
  int a = tok_a[(size_t)b * MAXTOK + t];
  int z = tok_z[(size_t)b * MAXTOK + t];
  int si = tok_sg[(size_t)b * MAXTOK + t];
  mask[o] = 1.0f;
  start[o] = (float)a;
  endo[o] = (float)z;
  cen[o] = (float)(((double)(a + z - 1) * 0.5) / 8191.0);
  span[o] = (float)((double)(z - a) / 8192.0);
  int s = seg_s[(size_t)b * MAXSEG + si];
  int e = seg_e[(size_t)b * MAXSEG + si];
  reg[o * 3 + 0] = (float)(seg_domp[(size_t)b * MAXSEG + si] / 8192.0);
  reg[o * 3 + 1] = (float)seg_bw[(size_t)b * MAXSEG + si];
  reg[o * 3 + 2] = (float)((double)(e - s) / 8192.0);
}

// ---------------------------------------------------------------------------
// Stage 7: patch gather (zero-fills padding).
// ---------------------------------------------------------------------------
__global__ __launch_bounds__(256) void k_patches(const float* __restrict__ x,
                                                 const int* __restrict__ tok_a,
                                                 const int* __restrict__ tok_z,
                                                 const int* __restrict__ ntok_g,
                                                 float* __restrict__ out, int mx) {
  int t = blockIdx.x, b = blockIdx.y;
  float* ob = out + (((size_t)b * (size_t)mx + t) * CC) * 16;
  if (t >= ntok_g[b]) {
    for (int e2 = threadIdx.x; e2 < CC * 16; e2 += 256) ob[e2] = 0.0f;
    return;
  }
  __shared__ int g0[16], g1[16];
  __shared__ float wS[16];
  if (threadIdx.x < 16) {
    int a = tok_a[(size_t)b * MAXTOK + t];
    int z = tok_z[(size_t)b * MAXTOK + t];
    int n = z - a;
    double src = ((double)threadIdx.x + 0.5) * ((double)n / 16.0) - 0.5;
    if (src < 0.0) src = 0.0;
    double hi = (double)n - 1.0;
    if (src > hi) src = hi;
    double fi = floor(src);
    int i0 = (int)fi;
    int i1 = i0 + 1;
    if (i1 > n - 1) i1 = n - 1;
    g0[threadIdx.x] = a + i0;
    g1[threadIdx.x] = a + i1;
    wS[threadIdx.x] = (float)(src - fi);
  }
  __syncthreads();
  const float* xb = x + (size_t)b * CC * LL;
  for (int e2 = threadIdx.x; e2 < CC * 16; e2 += 256) {
    int c = e2 >> 4, ai = e2 & 15;
    float wv = wS[ai];
    float v0 = xb[(size_t)c * LL + g0[ai]];
    float v1 = xb[(size_t)c * LL + g1[ai]];
    ob[e2] = v0 * (1.0f - wv) + v1 * wv;
  }
}

extern "C" void kernel_launch(void* const* d_in, const int* in_sizes, int n_in,
                              void* d_out, int out_size, void* d_ws, size_t ws_size,
                              hipStream_t stream) {
  (void)in_sizes; (void)n_in; (void)ws_size;
  const float* x = (const float*)d_in[0];
  float* out = (float*)d_out;
  // out_size = B*(1032*mx + 1)  -> recover mx
  long mx = ((long)out_size / BB - 1) / 1032;
  if (mx < 1) mx = 1;

  char* wp = (char*)d_ws;
  size_t off = 0;
  auto carve = [&](size_t bytes) -> void* {
    void* p = wp + off;
    off += (bytes + 255) & ~(size_t)255;
    return p;
  };
  double* agg = (double*)carve((size_t)BB * LL * 8);
  double* feat = (double*)carve((size_t)BB * NW * 3 * 8);
  double* segp = (double*)carve((size_t)BB * NBINS * 8);
  double* seg_domp = (double*)carve((size_t)BB * MAXSEG * 8);
  double* seg_bw = (double*)carve((size_t)BB * MAXSEG * 8);
  int* bnd = (int*)carve((size_t)BB * BNDCAP * 4);
  int* nbnd = (int*)carve((size_t)BB * 4);
  int* seg_s = (int*)carve((size_t)BB * MAXSEG * 4);
  int* seg_e = (int*)carve((size_t)BB * MAXSEG * 4);
  int* seg_pl = (int*)carve((size_t)BB * MAXSEG * 4);
  int* nseg = (int*)carve((size_t)BB * 4);
  int* tok_a = (int*)carve((size_t)BB * MAXTOK * 4);
  int* tok_z = (int*)carve((size_t)BB * MAXTOK * 4);
  int* tok_sg = (int*)carve((size_t)BB * MAXTOK * 4);
  int* ntok = (int*)carve((size_t)BB * 4);

  k_agg<<<(BB * LL + 255) / 256, 256, 0, stream>>>(x, agg);
  k_winfeat<<<(BB * NW + 255) / 256, 256, 0, stream>>>(agg, feat);
  k_dp<<<BB, 1024, 0, stream>>>(feat, bnd, nbnd, seg_s, seg_e, nseg);
  dim3 gb(NBINS / 256, BB);
  k_bins<<<gb, 512, 0, stream>>>(agg, bnd, nbnd, segp);
  k_segfin<<<BB, 256, 0, stream>>>(segp, seg_s, seg_e, nseg, seg_pl, seg_domp,
                                   seg_bw);
  k_tokens<<<1, 64, 0, stream>>>(seg_s, seg_e, seg_pl, nseg, tok_a, tok_z,
                                 tok_sg, ntok, out + (size_t)BB * (size_t)mx * 1032);
  dim3 gf(BB, (unsigned)((mx + 255) / 256));
  k_tokfill<<<gf, 256, 0, stream>>>(tok_a, tok_z, tok_sg, ntok, seg_s, seg_e,
                                    seg_domp, seg_bw, out, (int)mx);
  dim3 gp((unsigned)mx, BB);
  k_patches<<<gp, 256, 0, stream>>>(x, tok_a, tok_z, ntok, out, (int)mx);
}